// Round 2
// baseline (10076.119 us; speedup 1.0000x reference)
//
#include <hip/hip_runtime.h>
#include <hip/hip_bf16.h>

#define N_NODES 100000
#define N_EDGES 1600000
#define DIM 64
#define NL 4
#define NG 1024

// ---------------------------------------------------------------------------
// Workspace layout (floats):
//   h      @ 0                : N*64   node features
//   agg    @ 6.4M             : N*64   scatter target / z2 output (reused)
//   stats  @ 12.8M            : 768    [sum1(128) sq1(128) a1(128) c1(128)
//                                       sum2(64) sq2(64) a2(64) c2(64)]
//   pooled @ stats+768        : 1024*64
//   cnt    @ pooled+65536     : 1024
// total ~51.5 MB
// ---------------------------------------------------------------------------

__global__ void k_atom_embed(const int* __restrict__ x, const float* __restrict__ emb,
                             float* __restrict__ h) {
  int n = blockIdx.x * 4 + (threadIdx.x >> 6);
  int d = threadIdx.x & 63;
  if (n >= N_NODES) return;
  const int* xr = x + n * 9;
  float acc = 0.f;
#pragma unroll
  for (int c = 0; c < 9; ++c) acc += emb[(c * 100 + xr[c]) * 64 + d];
  h[n * 64 + d] = acc;
}

// one wave = one edge's 64 dims; 8 edges per wave, 4 waves per block
__global__ void k_edge_scatter(const int* __restrict__ ei, const int* __restrict__ ea,
                               const float* __restrict__ bond, const float* __restrict__ h,
                               float* __restrict__ agg) {
  __shared__ float sb[3 * 8 * 64];  // bond table for this layer, 6 KB
  for (int i = threadIdx.x; i < 1536; i += 256) sb[i] = bond[i];
  __syncthreads();
  int wave = threadIdx.x >> 6;
  int d = threadIdx.x & 63;
  int e0 = (blockIdx.x * 4 + wave) * 8;
#pragma unroll
  for (int i = 0; i < 8; ++i) {
    int e = e0 + i;
    if (e >= N_EDGES) break;
    int s = ei[e];             // scatter index (segment_sum over src)
    int t = ei[N_EDGES + e];   // gather index (h[dst])
    int a0 = ea[e * 3], a1 = ea[e * 3 + 1], a2 = ea[e * 3 + 2];
    float ef = sb[a0 * 64 + d] + sb[(8 + a1) * 64 + d] + sb[(16 + a2) * 64 + d];
    float m = fmaxf(h[t * 64 + d] + ef, 0.f);
    atomicAdd(&agg[s * 64 + d], m);
  }
}

// z = (1+eps)*h + agg; z1 = z@W1 + b1; accumulate per-column sum/sumsq only.
// 64 nodes/block, thread = (j in 0..127) x (half in 0..1)
// __launch_bounds__(256,1): allow ~128+ VGPRs so w[64] stays in registers
// (round-1 counters: VGPR_Count=64 forced a scratch spill -> 1.8 GB HBM/dispatch)
__global__ void __launch_bounds__(256, 1)
k_mm1_stats(const float* __restrict__ h, const float* __restrict__ agg,
            const float* __restrict__ W1, const float* __restrict__ b1,
            const float* __restrict__ epsp,
            float* __restrict__ sum1, float* __restrict__ sq1) {
  __shared__ __align__(16) float zl[4096];
  __shared__ float red[256];
  int tid = threadIdx.x;
  long nb = (long)blockIdx.x * 64;
  float ep = 1.0f + epsp[0];
  for (int i = tid; i < 4096; i += 256) {
    long g = nb * 64 + i;
    zl[i] = (g < (long)N_NODES * 64) ? fmaf(ep, h[g], agg[g]) : 0.f;
  }
  int j = tid & 127, half = tid >> 7;
  float w[64];
#pragma unroll
  for (int k = 0; k < 64; ++k) w[k] = W1[k * 128 + j];
  float bj = b1[j];
  __syncthreads();
  int nlim = (int)((long)N_NODES - nb < 64 ? (long)N_NODES - nb : 64);
  float s = 0.f, q = 0.f;
  for (int it = 0; it < 32; ++it) {
    int n = it * 2 + half;
    if (n >= nlim) break;
    const float4* zr = (const float4*)&zl[n * 64];
    float acc = bj;
#pragma unroll
    for (int kc = 0; kc < 16; ++kc) {
      float4 zv = zr[kc];
      acc = fmaf(zv.x, w[4 * kc + 0], acc);
      acc = fmaf(zv.y, w[4 * kc + 1], acc);
      acc = fmaf(zv.z, w[4 * kc + 2], acc);
      acc = fmaf(zv.w, w[4 * kc + 3], acc);
    }
    s += acc;
    q = fmaf(acc, acc, q);
  }
  red[tid] = s;
  __syncthreads();
  if (tid < 128) atomicAdd(&sum1[j], red[tid] + red[tid + 128]);
  __syncthreads();
  red[tid] = q;
  __syncthreads();
  if (tid < 128) atomicAdd(&sq1[j], red[tid] + red[tid + 128]);
}

__global__ void k_finalize(const float* __restrict__ sum, const float* __restrict__ sq,
                           const float* __restrict__ g, const float* __restrict__ b,
                           float* __restrict__ a, float* __restrict__ c) {
  int j = threadIdx.x;
  const float inv = 1.0f / (float)N_NODES;
  float m = sum[j] * inv;
  float v = sq[j] * inv - m * m;
  float r = rsqrtf(v + 1e-5f);
  float aa = g[j] * r;
  a[j] = aa;
  c[j] = fmaf(-m, aa, b[j]);
}

// recompute z1 = bn1(z@W1+b1) (affine a1,c1), relu, then z2 = z1@W2 + b2.
// z2 written in-place over agg (row-local, safe). Accumulates stats2.
__global__ void __launch_bounds__(256, 1)
k_mm2(const float* __restrict__ h, const float* __restrict__ agg,
      const float* __restrict__ W1, const float* __restrict__ b1,
      const float* __restrict__ a1, const float* __restrict__ c1,
      const float* __restrict__ W2, const float* __restrict__ b2,
      const float* __restrict__ epsp,
      float* __restrict__ z2, float* __restrict__ sum2, float* __restrict__ sq2) {
  __shared__ __align__(16) float zl[4096];
  __shared__ __align__(16) float z1l[8192];
  __shared__ float red[256];
  int tid = threadIdx.x;
  long nb = (long)blockIdx.x * 64;
  float ep = 1.0f + epsp[0];
  for (int i = tid; i < 4096; i += 256) {
    long g = nb * 64 + i;
    zl[i] = (g < (long)N_NODES * 64) ? fmaf(ep, h[g], agg[g]) : 0.f;
  }
  {
    int j = tid & 127, half = tid >> 7;
    float w[64];
#pragma unroll
    for (int k = 0; k < 64; ++k) w[k] = W1[k * 128 + j];
    float bj = b1[j], aj = a1[j], cj = c1[j];
    __syncthreads();
    for (int it = 0; it < 32; ++it) {
      int n = it * 2 + half;
      const float4* zr = (const float4*)&zl[n * 64];
      float acc = bj;
#pragma unroll
      for (int kc = 0; kc < 16; ++kc) {
        float4 zv = zr[kc];
        acc = fmaf(zv.x, w[4 * kc + 0], acc);
        acc = fmaf(zv.y, w[4 * kc + 1], acc);
        acc = fmaf(zv.z, w[4 * kc + 2], acc);
        acc = fmaf(zv.w, w[4 * kc + 3], acc);
      }
      z1l[n * 128 + j] = fmaxf(fmaf(acc, aj, cj), 0.f);
    }
  }
  __syncthreads();
  int j = tid & 63, q4 = tid >> 6;
  float bj = b2[j];
  float accB[16];
#pragma unroll
  for (int it = 0; it < 16; ++it) accB[it] = bj;
#pragma unroll
  for (int kc = 0; kc < 2; ++kc) {
    float w[64];
#pragma unroll
    for (int k = 0; k < 64; ++k) w[k] = W2[(kc * 64 + k) * 64 + j];
#pragma unroll
    for (int it = 0; it < 16; ++it) {
      int n = it * 4 + q4;
      const float4* zr = (const float4*)&z1l[n * 128 + kc * 64];
      float acc = accB[it];
#pragma unroll
      for (int kq = 0; kq < 16; ++kq) {
        float4 zv = zr[kq];
        acc = fmaf(zv.x, w[4 * kq + 0], acc);
        acc = fmaf(zv.y, w[4 * kq + 1], acc);
        acc = fmaf(zv.z, w[4 * kq + 2], acc);
        acc = fmaf(zv.w, w[4 * kq + 3], acc);
      }
      accB[it] = acc;
    }
  }
  float s = 0.f, q = 0.f;
#pragma unroll
  for (int it = 0; it < 16; ++it) {
    int n = it * 4 + q4;
    long gn = nb + n;
    if (gn < N_NODES) {
      float v = accB[it];
      z2[gn * 64 + j] = v;
      s += v;
      q = fmaf(v, v, q);
    }
  }
  red[tid] = s;
  __syncthreads();
  if (tid < 64) atomicAdd(&sum2[j], red[tid] + red[tid + 64] + red[tid + 128] + red[tid + 192]);
  __syncthreads();
  red[tid] = q;
  __syncthreads();
  if (tid < 64) atomicAdd(&sq2[j], red[tid] + red[tid + 64] + red[tid + 128] + red[tid + 192]);
}

__global__ void k_bn2(const float* __restrict__ z2, const float* __restrict__ a2,
                      const float* __restrict__ c2, float* __restrict__ h,
                      int do_relu, int do_pool, const int* __restrict__ batch,
                      float* __restrict__ pooled, float* __restrict__ cnt) {
  int n = blockIdx.x * 4 + (threadIdx.x >> 6);
  int d = threadIdx.x & 63;
  if (n >= N_NODES) return;
  float v = fmaf(z2[n * 64 + d], a2[d], c2[d]);
  if (do_relu) v = fmaxf(v, 0.f);
  h[n * 64 + d] = v;
  if (do_pool) {
    int g = batch[n];
    atomicAdd(&pooled[g * 64 + d], v);
    if (d == 0) atomicAdd(&cnt[g], 1.0f);
  }
}

__global__ void k_div(const float* __restrict__ pooled, const float* __restrict__ cnt,
                      float* __restrict__ out) {
  int g = blockIdx.x, d = threadIdx.x;
  out[g * 64 + d] = pooled[g * 64 + d] / (cnt[g] + 1e-9f);
}

extern "C" void kernel_launch(void* const* d_in, const int* in_sizes, int n_in,
                              void* d_out, int out_size, void* d_ws, size_t ws_size,
                              hipStream_t stream) {
  const int* x = (const int*)d_in[0];
  const int* ea = (const int*)d_in[1];
  const int* ei = (const int*)d_in[2];
  const int* batch = (const int*)d_in[3];
  const float* atom_emb = (const float*)d_in[4];
  const float* bond_emb = (const float*)d_in[5];
  const float* W1 = (const float*)d_in[6];
  const float* b1 = (const float*)d_in[7];
  const float* g1 = (const float*)d_in[8];
  const float* be1 = (const float*)d_in[9];
  const float* W2 = (const float*)d_in[10];
  const float* b2 = (const float*)d_in[11];
  const float* eps = (const float*)d_in[12];
  const float* bn_g = (const float*)d_in[13];
  const float* bn_b = (const float*)d_in[14];

  float* w = (float*)d_ws;
  float* h = w;
  float* agg = w + (size_t)N_NODES * 64;
  float* stats = agg + (size_t)N_NODES * 64;
  float* pooled = stats + 768;
  float* cnt = pooled + (size_t)NG * 64;

  hipMemsetAsync(pooled, 0, (NG * 64 + NG) * sizeof(float), stream);

  k_atom_embed<<<N_NODES / 4, 256, 0, stream>>>(x, atom_emb, h);

  for (int l = 0; l < NL; ++l) {
    float* sum1 = stats;
    float* sq1 = stats + 128;
    float* a1 = stats + 256;
    float* c1 = stats + 384;
    float* sum2 = stats + 512;
    float* sq2 = stats + 576;
    float* a2 = stats + 640;
    float* c2 = stats + 704;

    hipMemsetAsync(agg, 0, (size_t)N_NODES * 64 * sizeof(float), stream);
    hipMemsetAsync(stats, 0, 256 * sizeof(float), stream);   // sum1, sq1
    hipMemsetAsync(sum2, 0, 128 * sizeof(float), stream);    // sum2, sq2

    k_edge_scatter<<<(N_EDGES + 31) / 32, 256, 0, stream>>>(
        ei, ea, bond_emb + (size_t)l * 1536, h, agg);
    k_mm1_stats<<<(N_NODES + 63) / 64, 256, 0, stream>>>(
        h, agg, W1 + (size_t)l * 64 * 128, b1 + l * 128, eps + l, sum1, sq1);
    k_finalize<<<1, 128, 0, stream>>>(sum1, sq1, g1 + l * 128, be1 + l * 128, a1, c1);
    k_mm2<<<(N_NODES + 63) / 64, 256, 0, stream>>>(
        h, agg, W1 + (size_t)l * 64 * 128, b1 + l * 128, a1, c1,
        W2 + (size_t)l * 128 * 64, b2 + l * 64, eps + l, agg, sum2, sq2);
    k_finalize<<<1, 64, 0, stream>>>(sum2, sq2, bn_g + l * 64, bn_b + l * 64, a2, c2);
    k_bn2<<<N_NODES / 4, 256, 0, stream>>>(agg, a2, c2, h, (l != NL - 1) ? 1 : 0,
                                           (l == NL - 1) ? 1 : 0, batch, pooled, cnt);
  }
  k_div<<<NG, 64, 0, stream>>>(pooled, cnt, (float*)d_out);
}

// Round 3
// 3248.138 us; speedup vs baseline: 3.1021x; 3.1021x over previous
//
#include <hip/hip_runtime.h>
#include <hip/hip_bf16.h>

#define N_NODES 100000
#define N_EDGES 1600000
#define NL 4
#define NG 1024
#define ZS 68  // LDS z-tile stride (64+4): rows land on distinct bank quads

// ---------------------------------------------------------------------------
// ws layout (floats):
//   h      @ 0          : N*64
//   z      @ 6.4M       : N*64   (1+eps)*h + scatter; then z2 in-place
//   stats  @ 12.8M      : 4672   [cs 64 | M 4096 | s2 64 | q2 64 |
//                                 a1 128 | c1p 128 | a2 64 | c2 64]
//   pooled @ +4672      : NG*64
//   cnt    @ ...        : NG
// ---------------------------------------------------------------------------

__global__ void k_atom_embed(const int* __restrict__ x, const float* __restrict__ emb,
                             const float* __restrict__ epsp, float* __restrict__ h,
                             float* __restrict__ z) {
  int n = blockIdx.x * 4 + (threadIdx.x >> 6);
  int d = threadIdx.x & 63;
  const int* xr = x + n * 9;
  float acc = 0.f;
#pragma unroll
  for (int c = 0; c < 9; ++c) acc += emb[(c * 100 + xr[c]) * 64 + d];
  h[n * 64 + d] = acc;
  z[n * 64 + d] = (1.0f + epsp[0]) * acc;
}

// scatter edges into z (pre-filled with (1+eps)*h)
__global__ void k_edge_scatter(const int* __restrict__ ei, const int* __restrict__ ea,
                               const float* __restrict__ bond, const float* __restrict__ h,
                               float* __restrict__ z) {
  __shared__ float sb[1536];
  for (int i = threadIdx.x; i < 1536; i += 256) sb[i] = bond[i];
  __syncthreads();
  int wave = threadIdx.x >> 6;
  int d = threadIdx.x & 63;
  int e0 = (blockIdx.x * 4 + wave) * 8;
#pragma unroll
  for (int i = 0; i < 8; ++i) {
    int e = e0 + i;
    if (e >= N_EDGES) break;
    int s = ei[e];
    int t = ei[N_EDGES + e];
    int a0 = ea[e * 3], a1 = ea[e * 3 + 1], a2 = ea[e * 3 + 2];
    float ef = sb[a0 * 64 + d] + sb[(8 + a1) * 64 + d] + sb[(16 + a2) * 64 + d];
    float m = fmaxf(h[t * 64 + d] + ef, 0.f);
    atomicAdd(&z[s * 64 + d], m);
  }
}

// colsum(z) and M = z^T z  (256 nodes/block to amortize the 4096 global atomics)
__global__ void __launch_bounds__(256, 2)
k_zstats(const float* __restrict__ z, float* __restrict__ cs, float* __restrict__ M) {
  __shared__ float zl[64 * ZS];
  int tid = threadIdx.x;
  int a = tid >> 2, bq = (tid & 3) * 16;
  float accM[16];
#pragma unroll
  for (int c = 0; c < 16; ++c) accM[c] = 0.f;
  float accS = 0.f;
  for (int t = 0; t < 4; ++t) {
    int nb = (blockIdx.x * 4 + t) * 64;
    int nlim = N_NODES - nb;  // may be <=0 (tail): rows load as zero
    __syncthreads();
    for (int i = tid; i < 1024; i += 256) {
      int n = i >> 4, k4 = (i & 15) << 2;
      float4 v = make_float4(0.f, 0.f, 0.f, 0.f);
      if (n < nlim) v = *(const float4*)&z[(size_t)(nb + n) * 64 + k4];
      *(float4*)&zl[n * ZS + k4] = v;
    }
    __syncthreads();
    if (tid < 64) {
      float s = 0.f;
      for (int n = 0; n < 64; ++n) s += zl[n * ZS + tid];
      accS += s;
    }
#pragma unroll 4
    for (int n = 0; n < 64; ++n) {
      float va = zl[n * ZS + a];
      const float4* vb = (const float4*)&zl[n * ZS + bq];
#pragma unroll
      for (int c = 0; c < 4; ++c) {
        float4 v = vb[c];
        accM[c * 4 + 0] = fmaf(va, v.x, accM[c * 4 + 0]);
        accM[c * 4 + 1] = fmaf(va, v.y, accM[c * 4 + 1]);
        accM[c * 4 + 2] = fmaf(va, v.z, accM[c * 4 + 2]);
        accM[c * 4 + 3] = fmaf(va, v.w, accM[c * 4 + 3]);
      }
    }
  }
  if (tid < 64) atomicAdd(&cs[tid], accS);
#pragma unroll
  for (int c = 0; c < 16; ++c) atomicAdd(&M[a * 64 + bq + c], accM[c]);
}

// BN1 params from moments: m0 = cs.W1/N; var = (W1' M W1)jj/N - m0^2
// z1 = relu( (z@W1)*a1 + c1p ),  c1p = be1 - m0*a1  (b1 cancels in var)
__global__ void __launch_bounds__(128, 1)
k_fin1(const float* __restrict__ cs, const float* __restrict__ M,
       const float* __restrict__ W1, const float* __restrict__ b1,
       const float* __restrict__ g1, const float* __restrict__ be1,
       float* __restrict__ a1, float* __restrict__ c1p) {
  __shared__ float Ml[4096];
  __shared__ float csl[64];
  int j = threadIdx.x;
  for (int i = j; i < 4096; i += 128) Ml[i] = M[i];
  if (j < 64) csl[j] = cs[j];
  __syncthreads();
  float wcol[64];
#pragma unroll
  for (int k = 0; k < 64; ++k) wcol[k] = W1[k * 128 + j];
  float m0 = 0.f;
#pragma unroll
  for (int k = 0; k < 64; ++k) m0 = fmaf(csl[k], wcol[k], m0);
  m0 *= (1.0f / (float)N_NODES);
  float q = 0.f;
  for (int ka = 0; ka < 64; ++ka) {
    const float4* mr = (const float4*)&Ml[ka * 64];
    float t = 0.f;
#pragma unroll
    for (int kb = 0; kb < 16; ++kb) {
      float4 m = mr[kb];
      t = fmaf(m.x, wcol[kb * 4 + 0], t);
      t = fmaf(m.y, wcol[kb * 4 + 1], t);
      t = fmaf(m.z, wcol[kb * 4 + 2], t);
      t = fmaf(m.w, wcol[kb * 4 + 3], t);
    }
    q = fmaf(wcol[ka], t, q);
  }
  float var = q * (1.0f / (float)N_NODES) - m0 * m0;
  float r = rsqrtf(var + 1e-5f);
  float A = g1[j] * r;
  a1[j] = A;
  c1p[j] = fmaf(-m0, A, be1[j]);
  (void)b1;
}

// fused MLP: z@W1 -> bn1 affine+relu -> LDS (xor-swizzled) -> @W2 -> z (in-place) + stats2
__global__ void __launch_bounds__(256, 2)
k_mm2(const float* __restrict__ z, const float* __restrict__ W1g,
      const float* __restrict__ a1, const float* __restrict__ c1p,
      const float* __restrict__ W2g, const float* __restrict__ b2,
      float* __restrict__ zout, float* __restrict__ s2, float* __restrict__ q2) {
  __shared__ float sm[16512];
  float* zl = sm;            // [64][68] phase A
  float* w1l = sm + 4352;    // [64][128]
  float* z1l = sm;           // [64][32 granules] phase B (overlays zl/w1l head)
  float* w2l = sm + 8192;    // [128][64]
  float* ss = sm + 16384;
  float* sq = sm + 16448;
  int tid = threadIdx.x;
  int nb = blockIdx.x * 64;
  int nlim = N_NODES - nb;
  if (tid < 128) sm[16384 + tid] = 0.f;
  for (int i = tid; i < 1024; i += 256) {
    int n = i >> 4, k4 = (i & 15) << 2;
    float4 v = make_float4(0.f, 0.f, 0.f, 0.f);
    if (n < nlim) v = *(const float4*)&z[(size_t)(nb + n) * 64 + k4];
    *(float4*)&zl[n * ZS + k4] = v;
  }
  for (int i = tid; i < 2048; i += 256)
    *(float4*)&w1l[i * 4] = *(const float4*)&W1g[i * 4];
  __syncthreads();

  const int jg = tid & 15, ng = tid >> 4;
  const int j0 = jg * 8, n0 = ng * 4;
  float acc[4][8];
#pragma unroll
  for (int i = 0; i < 4; ++i)
#pragma unroll
    for (int c = 0; c < 8; ++c) acc[i][c] = 0.f;
#pragma unroll 2
  for (int k4 = 0; k4 < 16; ++k4) {
    float4 za[4];
#pragma unroll
    for (int i = 0; i < 4; ++i) za[i] = *(const float4*)&zl[(n0 + i) * ZS + k4 * 4];
#pragma unroll
    for (int kk = 0; kk < 4; ++kk) {
      const float4 w0 = *(const float4*)&w1l[(k4 * 4 + kk) * 128 + j0];
      const float4 w1 = *(const float4*)&w1l[(k4 * 4 + kk) * 128 + j0 + 4];
#pragma unroll
      for (int i = 0; i < 4; ++i) {
        const float zv = ((const float*)&za[i])[kk];
        acc[i][0] = fmaf(zv, w0.x, acc[i][0]);
        acc[i][1] = fmaf(zv, w0.y, acc[i][1]);
        acc[i][2] = fmaf(zv, w0.z, acc[i][2]);
        acc[i][3] = fmaf(zv, w0.w, acc[i][3]);
        acc[i][4] = fmaf(zv, w1.x, acc[i][4]);
        acc[i][5] = fmaf(zv, w1.y, acc[i][5]);
        acc[i][6] = fmaf(zv, w1.z, acc[i][6]);
        acc[i][7] = fmaf(zv, w1.w, acc[i][7]);
      }
    }
  }
  const float4 av0 = *(const float4*)&a1[j0], av1 = *(const float4*)&a1[j0 + 4];
  const float4 cv0 = *(const float4*)&c1p[j0], cv1 = *(const float4*)&c1p[j0 + 4];
  __syncthreads();  // all zl/w1l reads complete; accs in regs
  const int sxor = ng & 7;
#pragma unroll
  for (int i = 0; i < 4; ++i) {
    float4 v0, v1;
    v0.x = fmaxf(fmaf(acc[i][0], av0.x, cv0.x), 0.f);
    v0.y = fmaxf(fmaf(acc[i][1], av0.y, cv0.y), 0.f);
    v0.z = fmaxf(fmaf(acc[i][2], av0.z, cv0.z), 0.f);
    v0.w = fmaxf(fmaf(acc[i][3], av0.w, cv0.w), 0.f);
    v1.x = fmaxf(fmaf(acc[i][4], av1.x, cv1.x), 0.f);
    v1.y = fmaxf(fmaf(acc[i][5], av1.y, cv1.y), 0.f);
    v1.z = fmaxf(fmaf(acc[i][6], av1.z, cv1.z), 0.f);
    v1.w = fmaxf(fmaf(acc[i][7], av1.w, cv1.w), 0.f);
    const int g0 = (jg * 2) ^ sxor, g1i = (jg * 2 + 1) ^ sxor;
    *(float4*)&z1l[(n0 + i) * 128 + g0 * 4] = v0;
    *(float4*)&z1l[(n0 + i) * 128 + g1i * 4] = v1;
  }
  for (int i = tid; i < 2048; i += 256)
    *(float4*)&w2l[i * 4] = *(const float4*)&W2g[i * 4];
  __syncthreads();

  const int jb = (tid & 7) * 8, n0b = (tid >> 3) * 2;
  const float4 b20 = *(const float4*)&b2[jb], b21 = *(const float4*)&b2[jb + 4];
  float accB[2][8];
#pragma unroll
  for (int i = 0; i < 2; ++i) {
    accB[i][0] = b20.x; accB[i][1] = b20.y; accB[i][2] = b20.z; accB[i][3] = b20.w;
    accB[i][4] = b21.x; accB[i][5] = b21.y; accB[i][6] = b21.z; accB[i][7] = b21.w;
  }
#pragma unroll 2
  for (int k4 = 0; k4 < 32; ++k4) {
    float4 zb[2];
#pragma unroll
    for (int i = 0; i < 2; ++i) {
      const int n = n0b + i;
      const int gs = k4 ^ ((n >> 2) & 7);
      zb[i] = *(const float4*)&z1l[n * 128 + gs * 4];
    }
#pragma unroll
    for (int kk = 0; kk < 4; ++kk) {
      const float4 w0 = *(const float4*)&w2l[(k4 * 4 + kk) * 64 + jb];
      const float4 w1 = *(const float4*)&w2l[(k4 * 4 + kk) * 64 + jb + 4];
#pragma unroll
      for (int i = 0; i < 2; ++i) {
        const float zv = ((const float*)&zb[i])[kk];
        accB[i][0] = fmaf(zv, w0.x, accB[i][0]);
        accB[i][1] = fmaf(zv, w0.y, accB[i][1]);
        accB[i][2] = fmaf(zv, w0.z, accB[i][2]);
        accB[i][3] = fmaf(zv, w0.w, accB[i][3]);
        accB[i][4] = fmaf(zv, w1.x, accB[i][4]);
        accB[i][5] = fmaf(zv, w1.y, accB[i][5]);
        accB[i][6] = fmaf(zv, w1.z, accB[i][6]);
        accB[i][7] = fmaf(zv, w1.w, accB[i][7]);
      }
    }
  }
  float sj[8], qj[8];
#pragma unroll
  for (int c = 0; c < 8; ++c) { sj[c] = 0.f; qj[c] = 0.f; }
#pragma unroll
  for (int i = 0; i < 2; ++i) {
    const int n = n0b + i;
    if (n < nlim) {
      float4 o0, o1;
      o0.x = accB[i][0]; o0.y = accB[i][1]; o0.z = accB[i][2]; o0.w = accB[i][3];
      o1.x = accB[i][4]; o1.y = accB[i][5]; o1.z = accB[i][6]; o1.w = accB[i][7];
      *(float4*)&zout[(size_t)(nb + n) * 64 + jb] = o0;
      *(float4*)&zout[(size_t)(nb + n) * 64 + jb + 4] = o1;
#pragma unroll
      for (int c = 0; c < 8; ++c) {
        sj[c] += accB[i][c];
        qj[c] = fmaf(accB[i][c], accB[i][c], qj[c]);
      }
    }
  }
#pragma unroll
  for (int c = 0; c < 8; ++c) {
    atomicAdd(&ss[jb + c], sj[c]);
    atomicAdd(&sq[jb + c], qj[c]);
  }
  __syncthreads();
  if (tid < 64) {
    atomicAdd(&s2[tid], ss[tid]);
    atomicAdd(&q2[tid], sq[tid]);
  }
}

__global__ void k_finalize(const float* __restrict__ sum, const float* __restrict__ sq,
                           const float* __restrict__ g, const float* __restrict__ b,
                           float* __restrict__ a, float* __restrict__ c) {
  int j = threadIdx.x;
  const float inv = 1.0f / (float)N_NODES;
  float m = sum[j] * inv;
  float v = sq[j] * inv - m * m;
  float r = rsqrtf(v + 1e-5f);
  float aa = g[j] * r;
  a[j] = aa;
  c[j] = fmaf(-m, aa, b[j]);
}

// bn2 affine; non-last: relu, write h and z_next=(1+eps_next)*h; last: pool
__global__ void k_bn2(const float* __restrict__ z2, const float* __restrict__ a2,
                      const float* __restrict__ c2, float* __restrict__ h,
                      float* __restrict__ znext, const float* __restrict__ epsn,
                      int do_next, const int* __restrict__ batch,
                      float* __restrict__ pooled, float* __restrict__ cnt) {
  int n = blockIdx.x * 4 + (threadIdx.x >> 6);
  int d = threadIdx.x & 63;
  float v = fmaf(z2[n * 64 + d], a2[d], c2[d]);
  if (do_next) {
    v = fmaxf(v, 0.f);
    h[n * 64 + d] = v;
    znext[n * 64 + d] = (1.0f + epsn[0]) * v;
  } else {
    int g = batch[n];
    atomicAdd(&pooled[g * 64 + d], v);
    if (d == 0) atomicAdd(&cnt[g], 1.0f);
  }
}

__global__ void k_div(const float* __restrict__ pooled, const float* __restrict__ cnt,
                      float* __restrict__ out) {
  int g = blockIdx.x, d = threadIdx.x;
  out[g * 64 + d] = pooled[g * 64 + d] / (cnt[g] + 1e-9f);
}

extern "C" void kernel_launch(void* const* d_in, const int* in_sizes, int n_in,
                              void* d_out, int out_size, void* d_ws, size_t ws_size,
                              hipStream_t stream) {
  const int* x = (const int*)d_in[0];
  const int* ea = (const int*)d_in[1];
  const int* ei = (const int*)d_in[2];
  const int* batch = (const int*)d_in[3];
  const float* atom_emb = (const float*)d_in[4];
  const float* bond_emb = (const float*)d_in[5];
  const float* W1 = (const float*)d_in[6];
  const float* b1 = (const float*)d_in[7];
  const float* g1 = (const float*)d_in[8];
  const float* be1 = (const float*)d_in[9];
  const float* W2 = (const float*)d_in[10];
  const float* b2 = (const float*)d_in[11];
  const float* eps = (const float*)d_in[12];
  const float* bn_g = (const float*)d_in[13];
  const float* bn_b = (const float*)d_in[14];

  float* w = (float*)d_ws;
  float* h = w;
  float* z = w + (size_t)N_NODES * 64;
  float* stats = z + (size_t)N_NODES * 64;
  float* cs = stats;
  float* M = stats + 64;
  float* s2 = stats + 4160;
  float* q2 = stats + 4224;
  float* a1 = stats + 4288;
  float* c1p = stats + 4416;
  float* a2 = stats + 4544;
  float* c2 = stats + 4608;
  float* pooled = stats + 4672;
  float* cnt = pooled + (size_t)NG * 64;

  hipMemsetAsync(pooled, 0, (NG * 64 + NG) * sizeof(float), stream);
  k_atom_embed<<<N_NODES / 4, 256, 0, stream>>>(x, atom_emb, eps, h, z);

  for (int l = 0; l < NL; ++l) {
    hipMemsetAsync(stats, 0, 4288 * sizeof(float), stream);  // cs, M, s2, q2
    k_edge_scatter<<<(N_EDGES + 31) / 32, 256, 0, stream>>>(
        ei, ea, bond_emb + (size_t)l * 1536, h, z);
    k_zstats<<<(N_NODES + 255) / 256, 256, 0, stream>>>(z, cs, M);
    k_fin1<<<1, 128, 0, stream>>>(cs, M, W1 + (size_t)l * 8192, b1 + l * 128,
                                  g1 + l * 128, be1 + l * 128, a1, c1p);
    k_mm2<<<(N_NODES + 63) / 64, 256, 0, stream>>>(
        z, W1 + (size_t)l * 8192, a1, c1p, W2 + (size_t)l * 8192, b2 + l * 64,
        z, s2, q2);
    k_finalize<<<1, 64, 0, stream>>>(s2, q2, bn_g + l * 64, bn_b + l * 64, a2, c2);
    k_bn2<<<N_NODES / 4, 256, 0, stream>>>(z, a2, c2, h, z, eps + (l < NL - 1 ? l + 1 : 0),
                                           (l < NL - 1) ? 1 : 0, batch, pooled, cnt);
  }
  k_div<<<NG, 64, 0, stream>>>(pooled, cnt, (float*)d_out);
}

// Round 4
// 2311.892 us; speedup vs baseline: 4.3584x; 1.4050x over previous
//
#include <hip/hip_runtime.h>

#define N_NODES 100000
#define N_EDGES 1600000
#define NL 4
#define NG 1024
#define ZS 68  // LDS z-tile stride (64+4): rows land on distinct bank quads

// ---------------------------------------------------------------------------
// ws layout (floats):
//   A      @ 0          : N*64   h0 (atom embed); after layer-0 pull, reused as z2
//   B      @ 6.4M       : N*64   z accumulation (pull out, mm2 in)
//   stats  @ 12.8M      : 4672   [cs 64 | M 4096 | s2 64 | q2 64 |
//                                 a1 128 | c1p 128 | a2 64 | c2 64]
//   pooled @ +4672      : NG*64
//   cnt    @ ...        : NG
//   ints   @ ...        : ptr[100001] deg/cursor[100000] csr[1.6M] bs[391]
// total ~59 MB
// ---------------------------------------------------------------------------

__global__ void k_atom_embed(const int* __restrict__ x, const float* __restrict__ emb,
                             float* __restrict__ h) {
  int n = blockIdx.x * 4 + (threadIdx.x >> 6);
  int d = threadIdx.x & 63;
  const int* xr = x + n * 9;
  float acc = 0.f;
#pragma unroll
  for (int c = 0; c < 9; ++c) acc += emb[(c * 100 + xr[c]) * 64 + d];
  h[n * 64 + d] = acc;
}

// ---------------- CSR build (once per call; edge_index is loop-invariant) ----
__global__ void k_hist(const int* __restrict__ ei, int* __restrict__ deg) {
  int e = blockIdx.x * 256 + threadIdx.x;
  if (e < N_EDGES) atomicAdd(&deg[ei[e]], 1);
}

__global__ void k_scan1(const int* __restrict__ deg, int* __restrict__ bs) {
  __shared__ int s[256];
  int g = blockIdx.x * 256 + threadIdx.x;
  int v = (g < N_NODES) ? deg[g] : 0;
  s[threadIdx.x] = v;
  __syncthreads();
  for (int o = 128; o > 0; o >>= 1) {
    if (threadIdx.x < o) s[threadIdx.x] += s[threadIdx.x + o];
    __syncthreads();
  }
  if (threadIdx.x == 0) bs[blockIdx.x] = s[0];
}

__global__ void k_scan2(int* __restrict__ bs, int nblk) {
  __shared__ int s[512];
  int tid = threadIdx.x;
  int v = (tid < nblk) ? bs[tid] : 0;
  s[tid] = v;
  __syncthreads();
  for (int o = 1; o < 512; o <<= 1) {
    int t = (tid >= o) ? s[tid - o] : 0;
    __syncthreads();
    s[tid] += t;
    __syncthreads();
  }
  if (tid < nblk) bs[tid] = s[tid] - v;  // exclusive
}

__global__ void k_scan3(int* __restrict__ deg, const int* __restrict__ bs,
                        int* __restrict__ ptr) {
  __shared__ int s[256];
  int tid = threadIdx.x;
  int g = blockIdx.x * 256 + tid;
  int v = (g < N_NODES) ? deg[g] : 0;
  s[tid] = v;
  __syncthreads();
  for (int o = 1; o < 256; o <<= 1) {
    int t = (tid >= o) ? s[tid - o] : 0;
    __syncthreads();
    s[tid] += t;
    __syncthreads();
  }
  if (g < N_NODES) {
    int val = bs[blockIdx.x] + s[tid] - v;  // exclusive prefix
    ptr[g] = val;
    deg[g] = val;  // reuse deg as fill cursor
  }
  if (g == 0) ptr[N_NODES] = N_EDGES;
}

__global__ void k_fill(const int* __restrict__ ei, const int* __restrict__ ea,
                       int* __restrict__ cur, unsigned int* __restrict__ csr) {
  int e = blockIdx.x * 256 + threadIdx.x;
  if (e >= N_EDGES) return;
  int s = ei[e];
  unsigned int dst = (unsigned int)ei[N_EDGES + e];
  unsigned int b = (unsigned int)(ea[e * 3] | (ea[e * 3 + 1] << 3) | (ea[e * 3 + 2] << 6));
  int pos = atomicAdd(&cur[s], 1);
  csr[pos] = dst | (b << 17);
}

// ---------------- pull-mode aggregation (replaces atomic scatter) -----------
// wave = one node's 64 dims; applies prev-layer BN affine+relu to gathered rows
// on the fly (h never materialized). Writes z[n] = (1+eps)*act(n) + sum(msg).
// block 0 additionally zeroes the stats accumulators for this layer.
__global__ void __launch_bounds__(256)
k_pull(const float* __restrict__ src, const unsigned int* __restrict__ csr,
       const int* __restrict__ ptr, const float* __restrict__ bond,
       const float* __restrict__ aprev, const float* __restrict__ cprev,
       const float* __restrict__ epsp, int reluf,
       float* __restrict__ z, float* __restrict__ stats0) {
  __shared__ float sb[1536];
  for (int i = threadIdx.x; i < 1536; i += 256) sb[i] = bond[i];
  if (blockIdx.x == 0)
    for (int i = threadIdx.x; i < 4288; i += 256) stats0[i] = 0.f;
  __syncthreads();
  const int wave = threadIdx.x >> 6, d = threadIdx.x & 63;
  const float ep1 = 1.0f + epsp[0];
  const float aA = reluf ? aprev[d] : 1.0f;
  const float cC = reluf ? cprev[d] : 0.0f;
  const int n0 = blockIdx.x * 64 + wave * 16;
  for (int ii = 0; ii < 16; ++ii) {
    int n = n0 + ii;
    if (n >= N_NODES) break;
    int p0 = ptr[n], p1 = ptr[n + 1];
    float own = src[(size_t)n * 64 + d];
    if (reluf) own = fmaxf(fmaf(own, aA, cC), 0.f);
    float acc = ep1 * own;
    for (int base = p0; base < p1; base += 64) {
      int cnt = min(64, p1 - base);
      unsigned int mypk = (d < cnt) ? csr[base + d] : 0u;
      int i = 0;
      for (; i + 4 <= cnt; i += 4) {
        unsigned int pk0 = __shfl(mypk, i), pk1 = __shfl(mypk, i + 1),
                     pk2 = __shfl(mypk, i + 2), pk3 = __shfl(mypk, i + 3);
        float v0 = src[(size_t)(pk0 & 0x1FFFFu) * 64 + d];
        float v1 = src[(size_t)(pk1 & 0x1FFFFu) * 64 + d];
        float v2 = src[(size_t)(pk2 & 0x1FFFFu) * 64 + d];
        float v3 = src[(size_t)(pk3 & 0x1FFFFu) * 64 + d];
        if (reluf) {
          v0 = fmaxf(fmaf(v0, aA, cC), 0.f);
          v1 = fmaxf(fmaf(v1, aA, cC), 0.f);
          v2 = fmaxf(fmaf(v2, aA, cC), 0.f);
          v3 = fmaxf(fmaf(v3, aA, cC), 0.f);
        }
        unsigned int b0 = pk0 >> 17, b1 = pk1 >> 17, b2x = pk2 >> 17, b3 = pk3 >> 17;
        float e0 = sb[(b0 & 7) * 64 + d] + sb[(((b0 >> 3) & 7) + 8) * 64 + d] + sb[((b0 >> 6) + 16) * 64 + d];
        float e1 = sb[(b1 & 7) * 64 + d] + sb[(((b1 >> 3) & 7) + 8) * 64 + d] + sb[((b1 >> 6) + 16) * 64 + d];
        float e2 = sb[(b2x & 7) * 64 + d] + sb[(((b2x >> 3) & 7) + 8) * 64 + d] + sb[((b2x >> 6) + 16) * 64 + d];
        float e3 = sb[(b3 & 7) * 64 + d] + sb[(((b3 >> 3) & 7) + 8) * 64 + d] + sb[((b3 >> 6) + 16) * 64 + d];
        acc += fmaxf(v0 + e0, 0.f);
        acc += fmaxf(v1 + e1, 0.f);
        acc += fmaxf(v2 + e2, 0.f);
        acc += fmaxf(v3 + e3, 0.f);
      }
      for (; i < cnt; ++i) {
        unsigned int pk = __shfl(mypk, i);
        float v = src[(size_t)(pk & 0x1FFFFu) * 64 + d];
        if (reluf) v = fmaxf(fmaf(v, aA, cC), 0.f);
        unsigned int b = pk >> 17;
        float ef = sb[(b & 7) * 64 + d] + sb[(((b >> 3) & 7) + 8) * 64 + d] + sb[((b >> 6) + 16) * 64 + d];
        acc += fmaxf(v + ef, 0.f);
      }
    }
    z[(size_t)n * 64 + d] = acc;
  }
}

// colsum(z) and M = z^T z  (256 nodes/block to amortize the 4096 global atomics)
__global__ void __launch_bounds__(256, 2)
k_zstats(const float* __restrict__ z, float* __restrict__ cs, float* __restrict__ M) {
  __shared__ float zl[64 * ZS];
  int tid = threadIdx.x;
  int a = tid >> 2, bq = (tid & 3) * 16;
  float accM[16];
#pragma unroll
  for (int c = 0; c < 16; ++c) accM[c] = 0.f;
  float accS = 0.f;
  for (int t = 0; t < 4; ++t) {
    int nb = (blockIdx.x * 4 + t) * 64;
    int nlim = N_NODES - nb;  // may be <=0 (tail): rows load as zero
    __syncthreads();
    for (int i = tid; i < 1024; i += 256) {
      int n = i >> 4, k4 = (i & 15) << 2;
      float4 v = make_float4(0.f, 0.f, 0.f, 0.f);
      if (n < nlim) v = *(const float4*)&z[(size_t)(nb + n) * 64 + k4];
      *(float4*)&zl[n * ZS + k4] = v;
    }
    __syncthreads();
    if (tid < 64) {
      float s = 0.f;
      for (int n = 0; n < 64; ++n) s += zl[n * ZS + tid];
      accS += s;
    }
#pragma unroll 4
    for (int n = 0; n < 64; ++n) {
      float va = zl[n * ZS + a];
      const float4* vb = (const float4*)&zl[n * ZS + bq];
#pragma unroll
      for (int c = 0; c < 4; ++c) {
        float4 v = vb[c];
        accM[c * 4 + 0] = fmaf(va, v.x, accM[c * 4 + 0]);
        accM[c * 4 + 1] = fmaf(va, v.y, accM[c * 4 + 1]);
        accM[c * 4 + 2] = fmaf(va, v.z, accM[c * 4 + 2]);
        accM[c * 4 + 3] = fmaf(va, v.w, accM[c * 4 + 3]);
      }
    }
  }
  if (tid < 64) atomicAdd(&cs[tid], accS);
#pragma unroll
  for (int c = 0; c < 16; ++c) atomicAdd(&M[a * 64 + bq + c], accM[c]);
}

// BN1 params from moments: m0 = cs.W1/N; var = (W1' M W1)jj/N - m0^2
__global__ void __launch_bounds__(128, 1)
k_fin1(const float* __restrict__ cs, const float* __restrict__ M,
       const float* __restrict__ W1, const float* __restrict__ b1,
       const float* __restrict__ g1, const float* __restrict__ be1,
       float* __restrict__ a1, float* __restrict__ c1p) {
  __shared__ float Ml[4096];
  __shared__ float csl[64];
  int j = threadIdx.x;
  for (int i = j; i < 4096; i += 128) Ml[i] = M[i];
  if (j < 64) csl[j] = cs[j];
  __syncthreads();
  float wcol[64];
#pragma unroll
  for (int k = 0; k < 64; ++k) wcol[k] = W1[k * 128 + j];
  float m0 = 0.f;
#pragma unroll
  for (int k = 0; k < 64; ++k) m0 = fmaf(csl[k], wcol[k], m0);
  m0 *= (1.0f / (float)N_NODES);
  float q = 0.f;
  for (int ka = 0; ka < 64; ++ka) {
    const float4* mr = (const float4*)&Ml[ka * 64];
    float t = 0.f;
#pragma unroll
    for (int kb = 0; kb < 16; ++kb) {
      float4 m = mr[kb];
      t = fmaf(m.x, wcol[kb * 4 + 0], t);
      t = fmaf(m.y, wcol[kb * 4 + 1], t);
      t = fmaf(m.z, wcol[kb * 4 + 2], t);
      t = fmaf(m.w, wcol[kb * 4 + 3], t);
    }
    q = fmaf(wcol[ka], t, q);
  }
  float var = q * (1.0f / (float)N_NODES) - m0 * m0;
  float r = rsqrtf(var + 1e-5f);
  float A = g1[j] * r;
  a1[j] = A;
  c1p[j] = fmaf(-m0, A, be1[j]);
  (void)b1;
}

// fused MLP: z@W1 -> bn1 affine+relu -> LDS (xor-swizzled) -> @W2 -> z2 + stats2
__global__ void __launch_bounds__(256, 2)
k_mm2(const float* __restrict__ z, const float* __restrict__ W1g,
      const float* __restrict__ a1, const float* __restrict__ c1p,
      const float* __restrict__ W2g, const float* __restrict__ b2,
      float* __restrict__ zout, float* __restrict__ s2, float* __restrict__ q2) {
  __shared__ float sm[16512];
  float* zl = sm;            // [64][68] phase A
  float* w1l = sm + 4352;    // [64][128]
  float* z1l = sm;           // [64][32 granules] phase B (overlays zl/w1l head)
  float* w2l = sm + 8192;    // [128][64]
  float* ss = sm + 16384;
  float* sq = sm + 16448;
  int tid = threadIdx.x;
  int nb = blockIdx.x * 64;
  int nlim = N_NODES - nb;
  if (tid < 128) sm[16384 + tid] = 0.f;
  for (int i = tid; i < 1024; i += 256) {
    int n = i >> 4, k4 = (i & 15) << 2;
    float4 v = make_float4(0.f, 0.f, 0.f, 0.f);
    if (n < nlim) v = *(const float4*)&z[(size_t)(nb + n) * 64 + k4];
    *(float4*)&zl[n * ZS + k4] = v;
  }
  for (int i = tid; i < 2048; i += 256)
    *(float4*)&w1l[i * 4] = *(const float4*)&W1g[i * 4];
  __syncthreads();

  const int jg = tid & 15, ng = tid >> 4;
  const int j0 = jg * 8, n0 = ng * 4;
  float acc[4][8];
#pragma unroll
  for (int i = 0; i < 4; ++i)
#pragma unroll
    for (int c = 0; c < 8; ++c) acc[i][c] = 0.f;
#pragma unroll 2
  for (int k4 = 0; k4 < 16; ++k4) {
    float4 za[4];
#pragma unroll
    for (int i = 0; i < 4; ++i) za[i] = *(const float4*)&zl[(n0 + i) * ZS + k4 * 4];
#pragma unroll
    for (int kk = 0; kk < 4; ++kk) {
      const float4 w0 = *(const float4*)&w1l[(k4 * 4 + kk) * 128 + j0];
      const float4 w1 = *(const float4*)&w1l[(k4 * 4 + kk) * 128 + j0 + 4];
#pragma unroll
      for (int i = 0; i < 4; ++i) {
        const float zv = ((const float*)&za[i])[kk];
        acc[i][0] = fmaf(zv, w0.x, acc[i][0]);
        acc[i][1] = fmaf(zv, w0.y, acc[i][1]);
        acc[i][2] = fmaf(zv, w0.z, acc[i][2]);
        acc[i][3] = fmaf(zv, w0.w, acc[i][3]);
        acc[i][4] = fmaf(zv, w1.x, acc[i][4]);
        acc[i][5] = fmaf(zv, w1.y, acc[i][5]);
        acc[i][6] = fmaf(zv, w1.z, acc[i][6]);
        acc[i][7] = fmaf(zv, w1.w, acc[i][7]);
      }
    }
  }
  const float4 av0 = *(const float4*)&a1[j0], av1 = *(const float4*)&a1[j0 + 4];
  const float4 cv0 = *(const float4*)&c1p[j0], cv1 = *(const float4*)&c1p[j0 + 4];
  __syncthreads();  // all zl/w1l reads complete; accs in regs
  const int sxor = ng & 7;
#pragma unroll
  for (int i = 0; i < 4; ++i) {
    float4 v0, v1;
    v0.x = fmaxf(fmaf(acc[i][0], av0.x, cv0.x), 0.f);
    v0.y = fmaxf(fmaf(acc[i][1], av0.y, cv0.y), 0.f);
    v0.z = fmaxf(fmaf(acc[i][2], av0.z, cv0.z), 0.f);
    v0.w = fmaxf(fmaf(acc[i][3], av0.w, cv0.w), 0.f);
    v1.x = fmaxf(fmaf(acc[i][4], av1.x, cv1.x), 0.f);
    v1.y = fmaxf(fmaf(acc[i][5], av1.y, cv1.y), 0.f);
    v1.z = fmaxf(fmaf(acc[i][6], av1.z, cv1.z), 0.f);
    v1.w = fmaxf(fmaf(acc[i][7], av1.w, cv1.w), 0.f);
    const int g0 = (jg * 2) ^ sxor, g1i = (jg * 2 + 1) ^ sxor;
    *(float4*)&z1l[(n0 + i) * 128 + g0 * 4] = v0;
    *(float4*)&z1l[(n0 + i) * 128 + g1i * 4] = v1;
  }
  for (int i = tid; i < 2048; i += 256)
    *(float4*)&w2l[i * 4] = *(const float4*)&W2g[i * 4];
  __syncthreads();

  const int jb = (tid & 7) * 8, n0b = (tid >> 3) * 2;
  const float4 b20 = *(const float4*)&b2[jb], b21 = *(const float4*)&b2[jb + 4];
  float accB[2][8];
#pragma unroll
  for (int i = 0; i < 2; ++i) {
    accB[i][0] = b20.x; accB[i][1] = b20.y; accB[i][2] = b20.z; accB[i][3] = b20.w;
    accB[i][4] = b21.x; accB[i][5] = b21.y; accB[i][6] = b21.z; accB[i][7] = b21.w;
  }
#pragma unroll 2
  for (int k4 = 0; k4 < 32; ++k4) {
    float4 zb[2];
#pragma unroll
    for (int i = 0; i < 2; ++i) {
      const int n = n0b + i;
      const int gs = k4 ^ ((n >> 2) & 7);
      zb[i] = *(const float4*)&z1l[n * 128 + gs * 4];
    }
#pragma unroll
    for (int kk = 0; kk < 4; ++kk) {
      const float4 w0 = *(const float4*)&w2l[(k4 * 4 + kk) * 64 + jb];
      const float4 w1 = *(const float4*)&w2l[(k4 * 4 + kk) * 64 + jb + 4];
#pragma unroll
      for (int i = 0; i < 2; ++i) {
        const float zv = ((const float*)&zb[i])[kk];
        accB[i][0] = fmaf(zv, w0.x, accB[i][0]);
        accB[i][1] = fmaf(zv, w0.y, accB[i][1]);
        accB[i][2] = fmaf(zv, w0.z, accB[i][2]);
        accB[i][3] = fmaf(zv, w0.w, accB[i][3]);
        accB[i][4] = fmaf(zv, w1.x, accB[i][4]);
        accB[i][5] = fmaf(zv, w1.y, accB[i][5]);
        accB[i][6] = fmaf(zv, w1.z, accB[i][6]);
        accB[i][7] = fmaf(zv, w1.w, accB[i][7]);
      }
    }
  }
  float sj[8], qj[8];
#pragma unroll
  for (int c = 0; c < 8; ++c) { sj[c] = 0.f; qj[c] = 0.f; }
#pragma unroll
  for (int i = 0; i < 2; ++i) {
    const int n = n0b + i;
    if (n < nlim) {
      float4 o0, o1;
      o0.x = accB[i][0]; o0.y = accB[i][1]; o0.z = accB[i][2]; o0.w = accB[i][3];
      o1.x = accB[i][4]; o1.y = accB[i][5]; o1.z = accB[i][6]; o1.w = accB[i][7];
      *(float4*)&zout[(size_t)(nb + n) * 64 + jb] = o0;
      *(float4*)&zout[(size_t)(nb + n) * 64 + jb + 4] = o1;
#pragma unroll
      for (int c = 0; c < 8; ++c) {
        sj[c] += accB[i][c];
        qj[c] = fmaf(accB[i][c], accB[i][c], qj[c]);
      }
    }
  }
#pragma unroll
  for (int c = 0; c < 8; ++c) {
    atomicAdd(&ss[jb + c], sj[c]);
    atomicAdd(&sq[jb + c], qj[c]);
  }
  __syncthreads();
  if (tid < 64) {
    atomicAdd(&s2[tid], ss[tid]);
    atomicAdd(&q2[tid], sq[tid]);
  }
}

__global__ void k_finalize(const float* __restrict__ sum, const float* __restrict__ sq,
                           const float* __restrict__ g, const float* __restrict__ b,
                           float* __restrict__ a, float* __restrict__ c) {
  int j = threadIdx.x;
  const float inv = 1.0f / (float)N_NODES;
  float m = sum[j] * inv;
  float v = sq[j] * inv - m * m;
  float r = rsqrtf(v + 1e-5f);
  float aa = g[j] * r;
  a[j] = aa;
  c[j] = fmaf(-m, aa, b[j]);
}

// final: bn2 affine (no relu) + mean-pool
__global__ void k_pool(const float* __restrict__ z2, const float* __restrict__ a2,
                       const float* __restrict__ c2, const int* __restrict__ batch,
                       float* __restrict__ pooled, float* __restrict__ cnt) {
  int n = blockIdx.x * 4 + (threadIdx.x >> 6);
  int d = threadIdx.x & 63;
  float v = fmaf(z2[n * 64 + d], a2[d], c2[d]);
  int g = batch[n];
  atomicAdd(&pooled[g * 64 + d], v);
  if (d == 0) atomicAdd(&cnt[g], 1.0f);
}

__global__ void k_div(const float* __restrict__ pooled, const float* __restrict__ cnt,
                      float* __restrict__ out) {
  int g = blockIdx.x, d = threadIdx.x;
  out[g * 64 + d] = pooled[g * 64 + d] / (cnt[g] + 1e-9f);
}

extern "C" void kernel_launch(void* const* d_in, const int* in_sizes, int n_in,
                              void* d_out, int out_size, void* d_ws, size_t ws_size,
                              hipStream_t stream) {
  const int* x = (const int*)d_in[0];
  const int* ea = (const int*)d_in[1];
  const int* ei = (const int*)d_in[2];
  const int* batch = (const int*)d_in[3];
  const float* atom_emb = (const float*)d_in[4];
  const float* bond_emb = (const float*)d_in[5];
  const float* W1 = (const float*)d_in[6];
  const float* b1 = (const float*)d_in[7];
  const float* g1 = (const float*)d_in[8];
  const float* be1 = (const float*)d_in[9];
  const float* W2 = (const float*)d_in[10];
  const float* b2 = (const float*)d_in[11];
  const float* eps = (const float*)d_in[12];
  const float* bn_g = (const float*)d_in[13];
  const float* bn_b = (const float*)d_in[14];

  float* w = (float*)d_ws;
  float* A = w;                                 // h0, then z2 (aliased: h0's last
  float* B = w + (size_t)N_NODES * 64;          //  read is layer-0 pull)
  float* stats = B + (size_t)N_NODES * 64;
  float* cs = stats;
  float* M = stats + 64;
  float* s2 = stats + 4160;
  float* q2 = stats + 4224;
  float* a1 = stats + 4288;
  float* c1p = stats + 4416;
  float* a2 = stats + 4544;
  float* c2 = stats + 4608;
  float* pooled = stats + 4672;
  float* cnt = pooled + (size_t)NG * 64;
  int* ptr = (int*)(cnt + NG);                  // 100001
  int* deg = ptr + (N_NODES + 1);               // 100000 (then fill cursors)
  unsigned int* csr = (unsigned int*)(deg + N_NODES);  // 1.6M
  int* bs = (int*)(csr + N_EDGES);              // 391

  const int NBLK = (N_NODES + 255) / 256;  // 391

  hipMemsetAsync(pooled, 0, (NG * 64 + NG) * sizeof(float), stream);
  hipMemsetAsync(deg, 0, N_NODES * sizeof(int), stream);

  k_atom_embed<<<N_NODES / 4, 256, 0, stream>>>(x, atom_emb, A);

  // CSR build (once; reused across all 4 layers)
  k_hist<<<(N_EDGES + 255) / 256, 256, 0, stream>>>(ei, deg);
  k_scan1<<<NBLK, 256, 0, stream>>>(deg, bs);
  k_scan2<<<1, 512, 0, stream>>>(bs, NBLK);
  k_scan3<<<NBLK, 256, 0, stream>>>(deg, bs, ptr);
  k_fill<<<(N_EDGES + 255) / 256, 256, 0, stream>>>(ei, ea, deg, csr);

  for (int l = 0; l < NL; ++l) {
    const float* src = (l == 0) ? A : A;  // A is h0 for l=0, z2 for l>0
    k_pull<<<(N_NODES + 63) / 64, 256, 0, stream>>>(
        src, csr, ptr, bond_emb + (size_t)l * 1536, a2, c2, eps + l,
        (l > 0) ? 1 : 0, B, stats);
    k_zstats<<<NBLK, 256, 0, stream>>>(B, cs, M);
    k_fin1<<<1, 128, 0, stream>>>(cs, M, W1 + (size_t)l * 8192, b1 + l * 128,
                                  g1 + l * 128, be1 + l * 128, a1, c1p);
    k_mm2<<<(N_NODES + 63) / 64, 256, 0, stream>>>(
        B, W1 + (size_t)l * 8192, a1, c1p, W2 + (size_t)l * 8192, b2 + l * 64,
        A, s2, q2);
    k_finalize<<<1, 64, 0, stream>>>(s2, q2, bn_g + l * 64, bn_b + l * 64, a2, c2);
  }
  k_pool<<<N_NODES / 4, 256, 0, stream>>>(A, a2, c2, batch, pooled, cnt);
  k_div<<<NG, 64, 0, stream>>>(pooled, cnt, (float*)d_out);
}

// Round 5
// 1803.194 us; speedup vs baseline: 5.5879x; 1.2821x over previous
//
#include <hip/hip_runtime.h>

#define N_NODES 100000
#define N_EDGES 1600000
#define NL 4
#define NG 1024
#define ZS 68  // LDS z-tile stride (64+4)

// ---------------------------------------------------------------------------
// ws layout (floats):
//   A      @ 0          : N*64   h0 (atom embed); then z2 (in-place reuse)
//   B      @ 6.4M       : N*64   z accumulation (pull out, mm2 in)
//   stats  @ 12.8M      : 17152  [ 4 x (cs 64 | M 4096)  = 16640
//                                  s2 64 | q2 64 | a1 128 | c1p 128 | a2 64 | c2 64 ]
//   pooled @ +17152     : NG*64
//   cnt    @ ...        : NG
//   ints   @ ...        : ptr[100001] deg/cursor[100000] csr[1.6M] bs[391]
// ---------------------------------------------------------------------------

__global__ void k_atom_embed(const int* __restrict__ x, const float* __restrict__ emb,
                             float* __restrict__ h) {
  int n = blockIdx.x * 4 + (threadIdx.x >> 6);
  int d = threadIdx.x & 63;
  const int* xr = x + n * 9;
  float acc = 0.f;
#pragma unroll
  for (int c = 0; c < 9; ++c) acc += emb[(c * 100 + xr[c]) * 64 + d];
  h[n * 64 + d] = acc;
}

// ---------------- CSR build (once per call) --------------------------------
__global__ void k_hist(const int* __restrict__ ei, int* __restrict__ deg) {
  int e = blockIdx.x * 256 + threadIdx.x;
  if (e < N_EDGES) atomicAdd(&deg[ei[e]], 1);
}

__global__ void k_scan1(const int* __restrict__ deg, int* __restrict__ bs) {
  __shared__ int s[256];
  int g = blockIdx.x * 256 + threadIdx.x;
  int v = (g < N_NODES) ? deg[g] : 0;
  s[threadIdx.x] = v;
  __syncthreads();
  for (int o = 128; o > 0; o >>= 1) {
    if (threadIdx.x < o) s[threadIdx.x] += s[threadIdx.x + o];
    __syncthreads();
  }
  if (threadIdx.x == 0) bs[blockIdx.x] = s[0];
}

__global__ void k_scan2(int* __restrict__ bs, int nblk) {
  __shared__ int s[512];
  int tid = threadIdx.x;
  int v = (tid < nblk) ? bs[tid] : 0;
  s[tid] = v;
  __syncthreads();
  for (int o = 1; o < 512; o <<= 1) {
    int t = (tid >= o) ? s[tid - o] : 0;
    __syncthreads();
    s[tid] += t;
    __syncthreads();
  }
  if (tid < nblk) bs[tid] = s[tid] - v;  // exclusive
}

__global__ void k_scan3(int* __restrict__ deg, const int* __restrict__ bs,
                        int* __restrict__ ptr) {
  __shared__ int s[256];
  int tid = threadIdx.x;
  int g = blockIdx.x * 256 + tid;
  int v = (g < N_NODES) ? deg[g] : 0;
  s[tid] = v;
  __syncthreads();
  for (int o = 1; o < 256; o <<= 1) {
    int t = (tid >= o) ? s[tid - o] : 0;
    __syncthreads();
    s[tid] += t;
    __syncthreads();
  }
  if (g < N_NODES) {
    int val = bs[blockIdx.x] + s[tid] - v;
    ptr[g] = val;
    deg[g] = val;  // reuse deg as fill cursor
  }
  if (g == 0) ptr[N_NODES] = N_EDGES;
}

__global__ void k_fill(const int* __restrict__ ei, const int* __restrict__ ea,
                       int* __restrict__ cur, unsigned int* __restrict__ csr) {
  int e = blockIdx.x * 256 + threadIdx.x;
  if (e >= N_EDGES) return;
  int s = ei[e];
  unsigned int dst = (unsigned int)ei[N_EDGES + e];
  unsigned int b = (unsigned int)(ea[e * 3] | (ea[e * 3 + 1] << 3) | (ea[e * 3 + 2] << 6));
  int pos = atomicAdd(&cur[s], 1);
  csr[pos] = dst | (b << 17);
}

// ---------------- pull aggregation + fused BN1 moments ----------------------
// Block = 64 consecutive nodes (4 waves x 16). Wave computes z rows (applying
// prev-layer BN affine+relu to gathered rows on the fly), writes them to
// global z AND an LDS tile; then block computes colsum + z^T z for its tile
// (register 4x4 sub-tiles), atomically accumulating into copy (bid&3) of the
// replicated cs/M buffers (4-way replication cuts atomic contention 4x).
__global__ void __launch_bounds__(256)
k_pull(const float* __restrict__ src, const unsigned int* __restrict__ csr,
       const int* __restrict__ ptr, const float* __restrict__ bond,
       const float* __restrict__ aprev, const float* __restrict__ cprev,
       const float* __restrict__ epsp, int reluf,
       float* __restrict__ z, float* __restrict__ stats) {
  __shared__ float sb[1536];
  __shared__ __align__(16) float zl[64 * ZS];
  __shared__ float red[256];
  for (int i = threadIdx.x; i < 1536; i += 256) sb[i] = bond[i];
  __syncthreads();
  const int wave = threadIdx.x >> 6, d = threadIdx.x & 63;
  const float ep1 = 1.0f + epsp[0];
  const float aA = reluf ? aprev[d] : 1.0f;
  const float cC = reluf ? cprev[d] : 0.0f;
  const int n0 = blockIdx.x * 64 + wave * 16;
  for (int ii = 0; ii < 16; ++ii) {
    int n = n0 + ii;
    float acc = 0.f;
    if (n < N_NODES) {
      int p0 = ptr[n], p1 = ptr[n + 1];
      float own = src[(size_t)n * 64 + d];
      if (reluf) own = fmaxf(fmaf(own, aA, cC), 0.f);
      acc = ep1 * own;
      for (int base = p0; base < p1; base += 64) {
        int cnt = min(64, p1 - base);
        unsigned int mypk = (d < cnt) ? csr[base + d] : 0u;
        int i = 0;
        for (; i + 4 <= cnt; i += 4) {
          unsigned int pk0 = __shfl(mypk, i), pk1 = __shfl(mypk, i + 1),
                       pk2 = __shfl(mypk, i + 2), pk3 = __shfl(mypk, i + 3);
          float v0 = src[(size_t)(pk0 & 0x1FFFFu) * 64 + d];
          float v1 = src[(size_t)(pk1 & 0x1FFFFu) * 64 + d];
          float v2 = src[(size_t)(pk2 & 0x1FFFFu) * 64 + d];
          float v3 = src[(size_t)(pk3 & 0x1FFFFu) * 64 + d];
          if (reluf) {
            v0 = fmaxf(fmaf(v0, aA, cC), 0.f);
            v1 = fmaxf(fmaf(v1, aA, cC), 0.f);
            v2 = fmaxf(fmaf(v2, aA, cC), 0.f);
            v3 = fmaxf(fmaf(v3, aA, cC), 0.f);
          }
          unsigned int b0 = pk0 >> 17, b1 = pk1 >> 17, b2x = pk2 >> 17, b3 = pk3 >> 17;
          float e0 = sb[(b0 & 7) * 64 + d] + sb[(((b0 >> 3) & 7) + 8) * 64 + d] + sb[((b0 >> 6) + 16) * 64 + d];
          float e1 = sb[(b1 & 7) * 64 + d] + sb[(((b1 >> 3) & 7) + 8) * 64 + d] + sb[((b1 >> 6) + 16) * 64 + d];
          float e2 = sb[(b2x & 7) * 64 + d] + sb[(((b2x >> 3) & 7) + 8) * 64 + d] + sb[((b2x >> 6) + 16) * 64 + d];
          float e3 = sb[(b3 & 7) * 64 + d] + sb[(((b3 >> 3) & 7) + 8) * 64 + d] + sb[((b3 >> 6) + 16) * 64 + d];
          acc += fmaxf(v0 + e0, 0.f);
          acc += fmaxf(v1 + e1, 0.f);
          acc += fmaxf(v2 + e2, 0.f);
          acc += fmaxf(v3 + e3, 0.f);
        }
        for (; i < cnt; ++i) {
          unsigned int pk = __shfl(mypk, i);
          float v = src[(size_t)(pk & 0x1FFFFu) * 64 + d];
          if (reluf) v = fmaxf(fmaf(v, aA, cC), 0.f);
          unsigned int b = pk >> 17;
          float ef = sb[(b & 7) * 64 + d] + sb[(((b >> 3) & 7) + 8) * 64 + d] + sb[((b >> 6) + 16) * 64 + d];
          acc += fmaxf(v + ef, 0.f);
        }
      }
      z[(size_t)n * 64 + d] = acc;
    }
    zl[(wave * 16 + ii) * ZS + d] = acc;  // zero rows for tail nodes
  }
  __syncthreads();

  float* copy = stats + (blockIdx.x & 3) * 4160;  // [cs 64 | M 4096]
  // colsum: thread (wave,d) sums 16 rows, LDS-reduce 4 partials
  {
    float s = 0.f;
#pragma unroll
    for (int ii = 0; ii < 16; ++ii) s += zl[(wave * 16 + ii) * ZS + d];
    red[threadIdx.x] = s;
    __syncthreads();
    if (threadIdx.x < 64)
      atomicAdd(&copy[threadIdx.x],
                red[threadIdx.x] + red[threadIdx.x + 64] + red[threadIdx.x + 128] + red[threadIdx.x + 192]);
  }
  // M += tile^T tile: thread owns 4x4 sub-tile (ar, bc)
  const int ar = (threadIdx.x >> 4) * 4, bc = (threadIdx.x & 15) * 4;
  float m00 = 0.f, m01 = 0.f, m02 = 0.f, m03 = 0.f;
  float m10 = 0.f, m11 = 0.f, m12 = 0.f, m13 = 0.f;
  float m20 = 0.f, m21 = 0.f, m22 = 0.f, m23 = 0.f;
  float m30 = 0.f, m31 = 0.f, m32 = 0.f, m33 = 0.f;
#pragma unroll 4
  for (int n = 0; n < 64; ++n) {
    const float4 a = *(const float4*)&zl[n * ZS + ar];
    const float4 b = *(const float4*)&zl[n * ZS + bc];
    m00 = fmaf(a.x, b.x, m00); m01 = fmaf(a.x, b.y, m01); m02 = fmaf(a.x, b.z, m02); m03 = fmaf(a.x, b.w, m03);
    m10 = fmaf(a.y, b.x, m10); m11 = fmaf(a.y, b.y, m11); m12 = fmaf(a.y, b.z, m12); m13 = fmaf(a.y, b.w, m13);
    m20 = fmaf(a.z, b.x, m20); m21 = fmaf(a.z, b.y, m21); m22 = fmaf(a.z, b.z, m22); m23 = fmaf(a.z, b.w, m23);
    m30 = fmaf(a.w, b.x, m30); m31 = fmaf(a.w, b.y, m31); m32 = fmaf(a.w, b.z, m32); m33 = fmaf(a.w, b.w, m33);
  }
  float* M = copy + 64;
  atomicAdd(&M[(ar + 0) * 64 + bc + 0], m00); atomicAdd(&M[(ar + 0) * 64 + bc + 1], m01);
  atomicAdd(&M[(ar + 0) * 64 + bc + 2], m02); atomicAdd(&M[(ar + 0) * 64 + bc + 3], m03);
  atomicAdd(&M[(ar + 1) * 64 + bc + 0], m10); atomicAdd(&M[(ar + 1) * 64 + bc + 1], m11);
  atomicAdd(&M[(ar + 1) * 64 + bc + 2], m12); atomicAdd(&M[(ar + 1) * 64 + bc + 3], m13);
  atomicAdd(&M[(ar + 2) * 64 + bc + 0], m20); atomicAdd(&M[(ar + 2) * 64 + bc + 1], m21);
  atomicAdd(&M[(ar + 2) * 64 + bc + 2], m22); atomicAdd(&M[(ar + 2) * 64 + bc + 3], m23);
  atomicAdd(&M[(ar + 3) * 64 + bc + 0], m30); atomicAdd(&M[(ar + 3) * 64 + bc + 1], m31);
  atomicAdd(&M[(ar + 3) * 64 + bc + 2], m32); atomicAdd(&M[(ar + 3) * 64 + bc + 3], m33);
}

// BN1 params from moments (sums the 4 replicated copies)
__global__ void __launch_bounds__(128, 1)
k_fin1(const float* __restrict__ stats,
       const float* __restrict__ W1, const float* __restrict__ g1,
       const float* __restrict__ be1,
       float* __restrict__ a1, float* __restrict__ c1p) {
  __shared__ float Ml[4096];
  __shared__ float csl[64];
  int j = threadIdx.x;
  for (int i = j; i < 4096; i += 128)
    Ml[i] = stats[64 + i] + stats[4160 + 64 + i] + stats[8320 + 64 + i] + stats[12480 + 64 + i];
  if (j < 64) csl[j] = stats[j] + stats[4160 + j] + stats[8320 + j] + stats[12480 + j];
  __syncthreads();
  float wcol[64];
#pragma unroll
  for (int k = 0; k < 64; ++k) wcol[k] = W1[k * 128 + j];
  float m0 = 0.f;
#pragma unroll
  for (int k = 0; k < 64; ++k) m0 = fmaf(csl[k], wcol[k], m0);
  m0 *= (1.0f / (float)N_NODES);
  float q = 0.f;
  for (int ka = 0; ka < 64; ++ka) {
    const float4* mr = (const float4*)&Ml[ka * 64];
    float t = 0.f;
#pragma unroll
    for (int kb = 0; kb < 16; ++kb) {
      float4 m = mr[kb];
      t = fmaf(m.x, wcol[kb * 4 + 0], t);
      t = fmaf(m.y, wcol[kb * 4 + 1], t);
      t = fmaf(m.z, wcol[kb * 4 + 2], t);
      t = fmaf(m.w, wcol[kb * 4 + 3], t);
    }
    q = fmaf(wcol[ka], t, q);
  }
  float var = q * (1.0f / (float)N_NODES) - m0 * m0;
  float r = rsqrtf(var + 1e-5f);
  float A = g1[j] * r;
  a1[j] = A;
  c1p[j] = fmaf(-m0, A, be1[j]);
}

// fused MLP: z@W1 -> bn1 affine+relu -> LDS (swizzled) -> @W2 -> z2 + stats2
// lane jg owns output cols {4jg..4jg+3} u {64+4jg..64+4jg+3} so w1l reads hit
// consecutive bank quads (round-4 layout had a 4-way conflict, 5.2M cycles).
__global__ void __launch_bounds__(256, 2)
k_mm2(const float* __restrict__ z, const float* __restrict__ W1g,
      const float* __restrict__ a1, const float* __restrict__ c1p,
      const float* __restrict__ W2g, const float* __restrict__ b2,
      float* __restrict__ zout, float* __restrict__ s2, float* __restrict__ q2) {
  __shared__ __align__(16) float sm[16512];
  float* zl = sm;            // [64][68] phase A
  float* w1l = sm + 4352;    // [64][128]
  float* z1l = sm;           // [64][32 granules] phase B (overlays)
  float* w2l = sm + 8192;    // [128][64]
  float* ss = sm + 16384;
  float* sq = sm + 16448;
  int tid = threadIdx.x;
  int nb = blockIdx.x * 64;
  int nlim = N_NODES - nb;
  if (tid < 128) sm[16384 + tid] = 0.f;
  for (int i = tid; i < 1024; i += 256) {
    int n = i >> 4, k4 = (i & 15) << 2;
    float4 v = make_float4(0.f, 0.f, 0.f, 0.f);
    if (n < nlim) v = *(const float4*)&z[(size_t)(nb + n) * 64 + k4];
    *(float4*)&zl[n * ZS + k4] = v;
  }
  for (int i = tid; i < 2048; i += 256)
    *(float4*)&w1l[i * 4] = *(const float4*)&W1g[i * 4];
  __syncthreads();

  const int jg = tid & 15, ng = tid >> 4;
  const int n0 = ng * 4;
  float acc[4][8];
#pragma unroll
  for (int i = 0; i < 4; ++i)
#pragma unroll
    for (int c = 0; c < 8; ++c) acc[i][c] = 0.f;
#pragma unroll 2
  for (int k4 = 0; k4 < 16; ++k4) {
    float4 za[4];
#pragma unroll
    for (int i = 0; i < 4; ++i) za[i] = *(const float4*)&zl[(n0 + i) * ZS + k4 * 4];
#pragma unroll
    for (int kk = 0; kk < 4; ++kk) {
      const float4 w0 = *(const float4*)&w1l[(k4 * 4 + kk) * 128 + jg * 4];
      const float4 w1 = *(const float4*)&w1l[(k4 * 4 + kk) * 128 + 64 + jg * 4];
#pragma unroll
      for (int i = 0; i < 4; ++i) {
        const float zv = ((const float*)&za[i])[kk];
        acc[i][0] = fmaf(zv, w0.x, acc[i][0]);
        acc[i][1] = fmaf(zv, w0.y, acc[i][1]);
        acc[i][2] = fmaf(zv, w0.z, acc[i][2]);
        acc[i][3] = fmaf(zv, w0.w, acc[i][3]);
        acc[i][4] = fmaf(zv, w1.x, acc[i][4]);
        acc[i][5] = fmaf(zv, w1.y, acc[i][5]);
        acc[i][6] = fmaf(zv, w1.z, acc[i][6]);
        acc[i][7] = fmaf(zv, w1.w, acc[i][7]);
      }
    }
  }
  const float4 av0 = *(const float4*)&a1[jg * 4], av1 = *(const float4*)&a1[64 + jg * 4];
  const float4 cv0 = *(const float4*)&c1p[jg * 4], cv1 = *(const float4*)&c1p[64 + jg * 4];
  __syncthreads();  // zl/w1l reads done; accs in regs
  const int sxor = ng & 7;
#pragma unroll
  for (int i = 0; i < 4; ++i) {
    float4 v0, v1;
    v0.x = fmaxf(fmaf(acc[i][0], av0.x, cv0.x), 0.f);
    v0.y = fmaxf(fmaf(acc[i][1], av0.y, cv0.y), 0.f);
    v0.z = fmaxf(fmaf(acc[i][2], av0.z, cv0.z), 0.f);
    v0.w = fmaxf(fmaf(acc[i][3], av0.w, cv0.w), 0.f);
    v1.x = fmaxf(fmaf(acc[i][4], av1.x, cv1.x), 0.f);
    v1.y = fmaxf(fmaf(acc[i][5], av1.y, cv1.y), 0.f);
    v1.z = fmaxf(fmaf(acc[i][6], av1.z, cv1.z), 0.f);
    v1.w = fmaxf(fmaf(acc[i][7], av1.w, cv1.w), 0.f);
    const int g0 = jg ^ sxor, g1i = 16 + (jg ^ sxor);
    *(float4*)&z1l[(n0 + i) * 128 + g0 * 4] = v0;
    *(float4*)&z1l[(n0 + i) * 128 + g1i * 4] = v1;
  }
  for (int i = tid; i < 2048; i += 256)
    *(float4*)&w2l[i * 4] = *(const float4*)&W2g[i * 4];
  __syncthreads();

  const int jb = (tid & 7) * 8, n0b = (tid >> 3) * 2;
  const float4 b20 = *(const float4*)&b2[jb], b21 = *(const float4*)&b2[jb + 4];
  float accB[2][8];
#pragma unroll
  for (int i = 0; i < 2; ++i) {
    accB[i][0] = b20.x; accB[i][1] = b20.y; accB[i][2] = b20.z; accB[i][3] = b20.w;
    accB[i][4] = b21.x; accB[i][5] = b21.y; accB[i][6] = b21.z; accB[i][7] = b21.w;
  }
#pragma unroll 2
  for (int k4 = 0; k4 < 32; ++k4) {
    float4 zb[2];
#pragma unroll
    for (int i = 0; i < 2; ++i) {
      const int n = n0b + i;
      const int gs = k4 ^ ((n >> 2) & 7);
      zb[i] = *(const float4*)&z1l[n * 128 + gs * 4];
    }
#pragma unroll
    for (int kk = 0; kk < 4; ++kk) {
      const float4 w0 = *(const float4*)&w2l[(k4 * 4 + kk) * 64 + jb];
      const float4 w1 = *(const float4*)&w2l[(k4 * 4 + kk) * 64 + jb + 4];
#pragma unroll
      for (int i = 0; i < 2; ++i) {
        const float zv = ((const float*)&zb[i])[kk];
        accB[i][0] = fmaf(zv, w0.x, accB[i][0]);
        accB[i][1] = fmaf(zv, w0.y, accB[i][1]);
        accB[i][2] = fmaf(zv, w0.z, accB[i][2]);
        accB[i][3] = fmaf(zv, w0.w, accB[i][3]);
        accB[i][4] = fmaf(zv, w1.x, accB[i][4]);
        accB[i][5] = fmaf(zv, w1.y, accB[i][5]);
        accB[i][6] = fmaf(zv, w1.z, accB[i][6]);
        accB[i][7] = fmaf(zv, w1.w, accB[i][7]);
      }
    }
  }
  float sj[8], qj[8];
#pragma unroll
  for (int c = 0; c < 8; ++c) { sj[c] = 0.f; qj[c] = 0.f; }
#pragma unroll
  for (int i = 0; i < 2; ++i) {
    const int n = n0b + i;
    if (n < nlim) {
      float4 o0, o1;
      o0.x = accB[i][0]; o0.y = accB[i][1]; o0.z = accB[i][2]; o0.w = accB[i][3];
      o1.x = accB[i][4]; o1.y = accB[i][5]; o1.z = accB[i][6]; o1.w = accB[i][7];
      *(float4*)&zout[(size_t)(nb + n) * 64 + jb] = o0;
      *(float4*)&zout[(size_t)(nb + n) * 64 + jb + 4] = o1;
#pragma unroll
      for (int c = 0; c < 8; ++c) {
        sj[c] += accB[i][c];
        qj[c] = fmaf(accB[i][c], accB[i][c], qj[c]);
      }
    }
  }
#pragma unroll
  for (int c = 0; c < 8; ++c) {
    atomicAdd(&ss[jb + c], sj[c]);
    atomicAdd(&sq[jb + c], qj[c]);
  }
  __syncthreads();
  if (tid < 64) {
    atomicAdd(&s2[tid], ss[tid]);
    atomicAdd(&q2[tid], sq[tid]);
  }
}

__global__ void k_finalize(const float* __restrict__ sum, const float* __restrict__ sq,
                           const float* __restrict__ g, const float* __restrict__ b,
                           float* __restrict__ a, float* __restrict__ c) {
  int j = threadIdx.x;
  const float inv = 1.0f / (float)N_NODES;
  float m = sum[j] * inv;
  float v = sq[j] * inv - m * m;
  float r = rsqrtf(v + 1e-5f);
  float aa = g[j] * r;
  a[j] = aa;
  c[j] = fmaf(-m, aa, b[j]);
}

// final: bn2 affine (no relu) + mean-pool
__global__ void k_pool(const float* __restrict__ z2, const float* __restrict__ a2,
                       const float* __restrict__ c2, const int* __restrict__ batch,
                       float* __restrict__ pooled, float* __restrict__ cnt) {
  int n = blockIdx.x * 4 + (threadIdx.x >> 6);
  int d = threadIdx.x & 63;
  float v = fmaf(z2[n * 64 + d], a2[d], c2[d]);
  int g = batch[n];
  atomicAdd(&pooled[g * 64 + d], v);
  if (d == 0) atomicAdd(&cnt[g], 1.0f);
}

__global__ void k_div(const float* __restrict__ pooled, const float* __restrict__ cnt,
                      float* __restrict__ out) {
  int g = blockIdx.x, d = threadIdx.x;
  out[g * 64 + d] = pooled[g * 64 + d] / (cnt[g] + 1e-9f);
}

extern "C" void kernel_launch(void* const* d_in, const int* in_sizes, int n_in,
                              void* d_out, int out_size, void* d_ws, size_t ws_size,
                              hipStream_t stream) {
  const int* x = (const int*)d_in[0];
  const int* ea = (const int*)d_in[1];
  const int* ei = (const int*)d_in[2];
  const int* batch = (const int*)d_in[3];
  const float* atom_emb = (const float*)d_in[4];
  const float* bond_emb = (const float*)d_in[5];
  const float* W1 = (const float*)d_in[6];
  const float* g1 = (const float*)d_in[8];
  const float* be1 = (const float*)d_in[9];
  const float* W2 = (const float*)d_in[10];
  const float* b2 = (const float*)d_in[11];
  const float* eps = (const float*)d_in[12];
  const float* bn_g = (const float*)d_in[13];
  const float* bn_b = (const float*)d_in[14];

  float* w = (float*)d_ws;
  float* A = w;                                 // h0, then z2
  float* B = w + (size_t)N_NODES * 64;
  float* stats = B + (size_t)N_NODES * 64;      // 4x(cs|M) = 16640
  float* s2 = stats + 16640;
  float* q2 = stats + 16704;
  float* a1 = stats + 16768;
  float* c1p = stats + 16896;
  float* a2 = stats + 17024;
  float* c2 = stats + 17088;
  float* pooled = stats + 17152;
  float* cnt = pooled + (size_t)NG * 64;
  int* ptr = (int*)(cnt + NG);                  // 100001
  int* deg = ptr + (N_NODES + 1);               // 100000
  unsigned int* csr = (unsigned int*)(deg + N_NODES);  // 1.6M
  int* bs = (int*)(csr + N_EDGES);              // 391

  const int NBLK = (N_NODES + 255) / 256;  // 391
  const int NTILE = (N_NODES + 63) / 64;   // 1563

  hipMemsetAsync(pooled, 0, (NG * 64 + NG) * sizeof(float), stream);
  hipMemsetAsync(deg, 0, N_NODES * sizeof(int), stream);

  k_atom_embed<<<N_NODES / 4, 256, 0, stream>>>(x, atom_emb, A);

  // CSR build (once; reused across all 4 layers)
  k_hist<<<(N_EDGES + 255) / 256, 256, 0, stream>>>(ei, deg);
  k_scan1<<<NBLK, 256, 0, stream>>>(deg, bs);
  k_scan2<<<1, 512, 0, stream>>>(bs, NBLK);
  k_scan3<<<NBLK, 256, 0, stream>>>(deg, bs, ptr);
  k_fill<<<(N_EDGES + 255) / 256, 256, 0, stream>>>(ei, ea, deg, csr);

  for (int l = 0; l < NL; ++l) {
    hipMemsetAsync(stats, 0, 16768 * sizeof(float), stream);  // cs/M copies + s2/q2
    k_pull<<<NTILE, 256, 0, stream>>>(
        A, csr, ptr, bond_emb + (size_t)l * 1536, a2, c2, eps + l,
        (l > 0) ? 1 : 0, B, stats);
    k_fin1<<<1, 128, 0, stream>>>(stats, W1 + (size_t)l * 8192,
                                  g1 + l * 128, be1 + l * 128, a1, c1p);
    k_mm2<<<NTILE, 256, 0, stream>>>(
        B, W1 + (size_t)l * 8192, a1, c1p, W2 + (size_t)l * 8192, b2 + l * 64,
        A, s2, q2);
    k_finalize<<<1, 64, 0, stream>>>(s2, q2, bn_g + l * 64, bn_b + l * 64, a2, c2);
  }
  k_pool<<<N_NODES / 4, 256, 0, stream>>>(A, a2, c2, batch, pooled, cnt);
  k_div<<<NG, 64, 0, stream>>>(pooled, cnt, (float*)d_out);
}

// Round 6
// 1702.716 us; speedup vs baseline: 5.9177x; 1.0590x over previous
//
#include <hip/hip_runtime.h>

#define N_NODES 100000
#define N_EDGES 1600000
#define NL 4
#define NG 1024
#define ZS 68  // LDS z-tile stride (64+4)

// ---------------------------------------------------------------------------
// ws layout (floats):
//   A      @ 0          : N*64   h0 (atom embed); then z2 (in-place reuse)
//   B      @ 6.4M       : N*64   z accumulation (pull out, zstats/mm2 in)
//   stats  @ 12.8M      : 17152  [ 4 x (cs 64 | M 4096)  = 16640
//                                  s2 64 | q2 64 | a1 128 | c1p 128 | a2 64 | c2 64 ]
//   pooled @ +17152     : NG*64
//   cnt    @ ...        : NG
//   ints   @ ...        : ptr[100001] deg/cursor[100000] csr[1.6M] bs[391]
// ---------------------------------------------------------------------------

__global__ void k_atom_embed(const int* __restrict__ x, const float* __restrict__ emb,
                             float* __restrict__ h) {
  int n = blockIdx.x * 4 + (threadIdx.x >> 6);
  int d = threadIdx.x & 63;
  const int* xr = x + n * 9;
  float acc = 0.f;
#pragma unroll
  for (int c = 0; c < 9; ++c) acc += emb[(c * 100 + xr[c]) * 64 + d];
  h[n * 64 + d] = acc;
}

// ---------------- CSR build (once per call) --------------------------------
__global__ void k_hist(const int* __restrict__ ei, int* __restrict__ deg) {
  int e = blockIdx.x * 256 + threadIdx.x;
  if (e < N_EDGES) atomicAdd(&deg[ei[e]], 1);
}

__global__ void k_scan1(const int* __restrict__ deg, int* __restrict__ bs) {
  __shared__ int s[256];
  int g = blockIdx.x * 256 + threadIdx.x;
  int v = (g < N_NODES) ? deg[g] : 0;
  s[threadIdx.x] = v;
  __syncthreads();
  for (int o = 128; o > 0; o >>= 1) {
    if (threadIdx.x < o) s[threadIdx.x] += s[threadIdx.x + o];
    __syncthreads();
  }
  if (threadIdx.x == 0) bs[blockIdx.x] = s[0];
}

__global__ void k_scan2(int* __restrict__ bs, int nblk) {
  __shared__ int s[512];
  int tid = threadIdx.x;
  int v = (tid < nblk) ? bs[tid] : 0;
  s[tid] = v;
  __syncthreads();
  for (int o = 1; o < 512; o <<= 1) {
    int t = (tid >= o) ? s[tid - o] : 0;
    __syncthreads();
    s[tid] += t;
    __syncthreads();
  }
  if (tid < nblk) bs[tid] = s[tid] - v;  // exclusive
}

__global__ void k_scan3(int* __restrict__ deg, const int* __restrict__ bs,
                        int* __restrict__ ptr) {
  __shared__ int s[256];
  int tid = threadIdx.x;
  int g = blockIdx.x * 256 + tid;
  int v = (g < N_NODES) ? deg[g] : 0;
  s[tid] = v;
  __syncthreads();
  for (int o = 1; o < 256; o <<= 1) {
    int t = (tid >= o) ? s[tid - o] : 0;
    __syncthreads();
    s[tid] += t;
    __syncthreads();
  }
  if (g < N_NODES) {
    int val = bs[blockIdx.x] + s[tid] - v;
    ptr[g] = val;
    deg[g] = val;  // reuse deg as fill cursor
  }
  if (g == 0) ptr[N_NODES] = N_EDGES;
}

__global__ void k_fill(const int* __restrict__ ei, const int* __restrict__ ea,
                       int* __restrict__ cur, unsigned int* __restrict__ csr) {
  int e = blockIdx.x * 256 + threadIdx.x;
  if (e >= N_EDGES) return;
  int s = ei[e];
  unsigned int dst = (unsigned int)ei[N_EDGES + e];
  unsigned int b = (unsigned int)(ea[e * 3] | (ea[e * 3 + 1] << 3) | (ea[e * 3 + 2] << 6));
  int pos = atomicAdd(&cur[s], 1);
  csr[pos] = dst | (b << 17);
}

// ---------------- pull-mode aggregation -------------------------------------
// Wave = one node's 64 dims, 8 nodes per wave, 32 per block (100000 = 3125*32,
// exact). LDS = 6KB bond table only -> occupancy capped by waves (32/CU), not
// LDS (round-5: 24.5KB zl tile capped at ~12-24 waves -> 38% occupancy, 28%
// VALUBusy: latency-bound on L2-miss gathers). Moments moved to k_zstats.
__global__ void __launch_bounds__(256)
k_pull(const float* __restrict__ src, const unsigned int* __restrict__ csr,
       const int* __restrict__ ptr, const float* __restrict__ bond,
       const float* __restrict__ aprev, const float* __restrict__ cprev,
       const float* __restrict__ epsp, int reluf,
       float* __restrict__ z) {
  __shared__ float sb[1536];
  for (int i = threadIdx.x; i < 1536; i += 256) sb[i] = bond[i];
  __syncthreads();
  const int wave = threadIdx.x >> 6, d = threadIdx.x & 63;
  const float ep1 = 1.0f + epsp[0];
  const float aA = reluf ? aprev[d] : 1.0f;
  const float cC = reluf ? cprev[d] : 0.0f;
  const int n0 = blockIdx.x * 32 + wave * 8;
#pragma unroll
  for (int ii = 0; ii < 8; ++ii) {
    int n = n0 + ii;
    int p0 = ptr[n], p1 = ptr[n + 1];
    float own = src[(size_t)n * 64 + d];
    if (reluf) own = fmaxf(fmaf(own, aA, cC), 0.f);
    float acc = ep1 * own;
    for (int base = p0; base < p1; base += 64) {
      int cnt = min(64, p1 - base);
      unsigned int mypk = (d < cnt) ? csr[base + d] : 0u;
      int i = 0;
      for (; i + 4 <= cnt; i += 4) {
        unsigned int pk0 = __shfl(mypk, i), pk1 = __shfl(mypk, i + 1),
                     pk2 = __shfl(mypk, i + 2), pk3 = __shfl(mypk, i + 3);
        float v0 = src[(size_t)(pk0 & 0x1FFFFu) * 64 + d];
        float v1 = src[(size_t)(pk1 & 0x1FFFFu) * 64 + d];
        float v2 = src[(size_t)(pk2 & 0x1FFFFu) * 64 + d];
        float v3 = src[(size_t)(pk3 & 0x1FFFFu) * 64 + d];
        if (reluf) {
          v0 = fmaxf(fmaf(v0, aA, cC), 0.f);
          v1 = fmaxf(fmaf(v1, aA, cC), 0.f);
          v2 = fmaxf(fmaf(v2, aA, cC), 0.f);
          v3 = fmaxf(fmaf(v3, aA, cC), 0.f);
        }
        unsigned int b0 = pk0 >> 17, b1 = pk1 >> 17, b2x = pk2 >> 17, b3 = pk3 >> 17;
        float e0 = sb[(b0 & 7) * 64 + d] + sb[(((b0 >> 3) & 7) + 8) * 64 + d] + sb[((b0 >> 6) + 16) * 64 + d];
        float e1 = sb[(b1 & 7) * 64 + d] + sb[(((b1 >> 3) & 7) + 8) * 64 + d] + sb[((b1 >> 6) + 16) * 64 + d];
        float e2 = sb[(b2x & 7) * 64 + d] + sb[(((b2x >> 3) & 7) + 8) * 64 + d] + sb[((b2x >> 6) + 16) * 64 + d];
        float e3 = sb[(b3 & 7) * 64 + d] + sb[(((b3 >> 3) & 7) + 8) * 64 + d] + sb[((b3 >> 6) + 16) * 64 + d];
        acc += fmaxf(v0 + e0, 0.f);
        acc += fmaxf(v1 + e1, 0.f);
        acc += fmaxf(v2 + e2, 0.f);
        acc += fmaxf(v3 + e3, 0.f);
      }
      for (; i < cnt; ++i) {
        unsigned int pk = __shfl(mypk, i);
        float v = src[(size_t)(pk & 0x1FFFFu) * 64 + d];
        if (reluf) v = fmaxf(fmaf(v, aA, cC), 0.f);
        unsigned int b = pk >> 17;
        float ef = sb[(b & 7) * 64 + d] + sb[(((b >> 3) & 7) + 8) * 64 + d] + sb[((b >> 6) + 16) * 64 + d];
        acc += fmaxf(v + ef, 0.f);
      }
    }
    z[(size_t)n * 64 + d] = acc;
  }
}

// ---------------- BN1 moments: colsum(z), M = z^T z -------------------------
// 1563 blocks x 64-node tile; register 4x4 M sub-tiles; 4-way replicated
// atomic targets (round-4's 391-block serial-chain design was 271us; this is
// the register-tiled structure that ran inside round-5's pull).
__global__ void __launch_bounds__(256)
k_zstats(const float* __restrict__ z, float* __restrict__ stats) {
  __shared__ __align__(16) float zl[64 * ZS];
  __shared__ float red[256];
  int tid = threadIdx.x;
  int nb = blockIdx.x * 64;
  int nlim = N_NODES - nb;
  for (int i = tid; i < 1024; i += 256) {
    int n = i >> 4, k4 = (i & 15) << 2;
    float4 v = make_float4(0.f, 0.f, 0.f, 0.f);
    if (n < nlim) v = *(const float4*)&z[(size_t)(nb + n) * 64 + k4];
    *(float4*)&zl[n * ZS + k4] = v;
  }
  __syncthreads();
  float* copy = stats + (blockIdx.x & 3) * 4160;  // [cs 64 | M 4096]
  {
    int wave = tid >> 6, d = tid & 63;
    float s = 0.f;
#pragma unroll
    for (int ii = 0; ii < 16; ++ii) s += zl[(wave * 16 + ii) * ZS + d];
    red[tid] = s;
    __syncthreads();
    if (tid < 64)
      atomicAdd(&copy[tid], red[tid] + red[tid + 64] + red[tid + 128] + red[tid + 192]);
  }
  const int ar = (tid >> 4) * 4, bc = (tid & 15) * 4;
  float m00 = 0.f, m01 = 0.f, m02 = 0.f, m03 = 0.f;
  float m10 = 0.f, m11 = 0.f, m12 = 0.f, m13 = 0.f;
  float m20 = 0.f, m21 = 0.f, m22 = 0.f, m23 = 0.f;
  float m30 = 0.f, m31 = 0.f, m32 = 0.f, m33 = 0.f;
#pragma unroll 4
  for (int n = 0; n < 64; ++n) {
    const float4 a = *(const float4*)&zl[n * ZS + ar];
    const float4 b = *(const float4*)&zl[n * ZS + bc];
    m00 = fmaf(a.x, b.x, m00); m01 = fmaf(a.x, b.y, m01); m02 = fmaf(a.x, b.z, m02); m03 = fmaf(a.x, b.w, m03);
    m10 = fmaf(a.y, b.x, m10); m11 = fmaf(a.y, b.y, m11); m12 = fmaf(a.y, b.z, m12); m13 = fmaf(a.y, b.w, m13);
    m20 = fmaf(a.z, b.x, m20); m21 = fmaf(a.z, b.y, m21); m22 = fmaf(a.z, b.z, m22); m23 = fmaf(a.z, b.w, m23);
    m30 = fmaf(a.w, b.x, m30); m31 = fmaf(a.w, b.y, m31); m32 = fmaf(a.w, b.z, m32); m33 = fmaf(a.w, b.w, m33);
  }
  float* M = copy + 64;
  atomicAdd(&M[(ar + 0) * 64 + bc + 0], m00); atomicAdd(&M[(ar + 0) * 64 + bc + 1], m01);
  atomicAdd(&M[(ar + 0) * 64 + bc + 2], m02); atomicAdd(&M[(ar + 0) * 64 + bc + 3], m03);
  atomicAdd(&M[(ar + 1) * 64 + bc + 0], m10); atomicAdd(&M[(ar + 1) * 64 + bc + 1], m11);
  atomicAdd(&M[(ar + 1) * 64 + bc + 2], m12); atomicAdd(&M[(ar + 1) * 64 + bc + 3], m13);
  atomicAdd(&M[(ar + 2) * 64 + bc + 0], m20); atomicAdd(&M[(ar + 2) * 64 + bc + 1], m21);
  atomicAdd(&M[(ar + 2) * 64 + bc + 2], m22); atomicAdd(&M[(ar + 2) * 64 + bc + 3], m23);
  atomicAdd(&M[(ar + 3) * 64 + bc + 0], m30); atomicAdd(&M[(ar + 3) * 64 + bc + 1], m31);
  atomicAdd(&M[(ar + 3) * 64 + bc + 2], m32); atomicAdd(&M[(ar + 3) * 64 + bc + 3], m33);
}

// BN1 params from moments (sums the 4 replicated copies)
__global__ void __launch_bounds__(128, 1)
k_fin1(const float* __restrict__ stats,
       const float* __restrict__ W1, const float* __restrict__ g1,
       const float* __restrict__ be1,
       float* __restrict__ a1, float* __restrict__ c1p) {
  __shared__ float Ml[4096];
  __shared__ float csl[64];
  int j = threadIdx.x;
  for (int i = j; i < 4096; i += 128)
    Ml[i] = stats[64 + i] + stats[4160 + 64 + i] + stats[8320 + 64 + i] + stats[12480 + 64 + i];
  if (j < 64) csl[j] = stats[j] + stats[4160 + j] + stats[8320 + j] + stats[12480 + j];
  __syncthreads();
  float wcol[64];
#pragma unroll
  for (int k = 0; k < 64; ++k) wcol[k] = W1[k * 128 + j];
  float m0 = 0.f;
#pragma unroll
  for (int k = 0; k < 64; ++k) m0 = fmaf(csl[k], wcol[k], m0);
  m0 *= (1.0f / (float)N_NODES);
  float q = 0.f;
  for (int ka = 0; ka < 64; ++ka) {
    const float4* mr = (const float4*)&Ml[ka * 64];
    float t = 0.f;
#pragma unroll
    for (int kb = 0; kb < 16; ++kb) {
      float4 m = mr[kb];
      t = fmaf(m.x, wcol[kb * 4 + 0], t);
      t = fmaf(m.y, wcol[kb * 4 + 1], t);
      t = fmaf(m.z, wcol[kb * 4 + 2], t);
      t = fmaf(m.w, wcol[kb * 4 + 3], t);
    }
    q = fmaf(wcol[ka], t, q);
  }
  float var = q * (1.0f / (float)N_NODES) - m0 * m0;
  float r = rsqrtf(var + 1e-5f);
  float A = g1[j] * r;
  a1[j] = A;
  c1p[j] = fmaf(-m0, A, be1[j]);
}

// fused MLP: z@W1 -> bn1 affine+relu -> LDS (swizzled) -> @W2 -> z2 + stats2
__global__ void __launch_bounds__(256, 2)
k_mm2(const float* __restrict__ z, const float* __restrict__ W1g,
      const float* __restrict__ a1, const float* __restrict__ c1p,
      const float* __restrict__ W2g, const float* __restrict__ b2,
      float* __restrict__ zout, float* __restrict__ s2, float* __restrict__ q2) {
  __shared__ __align__(16) float sm[16512];
  float* zl = sm;            // [64][68] phase A
  float* w1l = sm + 4352;    // [64][128]
  float* z1l = sm;           // [64][32 granules] phase B (overlays)
  float* w2l = sm + 8192;    // [128][64]
  float* ss = sm + 16384;
  float* sq = sm + 16448;
  int tid = threadIdx.x;
  int nb = blockIdx.x * 64;
  int nlim = N_NODES - nb;
  if (tid < 128) sm[16384 + tid] = 0.f;
  for (int i = tid; i < 1024; i += 256) {
    int n = i >> 4, k4 = (i & 15) << 2;
    float4 v = make_float4(0.f, 0.f, 0.f, 0.f);
    if (n < nlim) v = *(const float4*)&z[(size_t)(nb + n) * 64 + k4];
    *(float4*)&zl[n * ZS + k4] = v;
  }
  for (int i = tid; i < 2048; i += 256)
    *(float4*)&w1l[i * 4] = *(const float4*)&W1g[i * 4];
  __syncthreads();

  const int jg = tid & 15, ng = tid >> 4;
  const int n0 = ng * 4;
  float acc[4][8];
#pragma unroll
  for (int i = 0; i < 4; ++i)
#pragma unroll
    for (int c = 0; c < 8; ++c) acc[i][c] = 0.f;
#pragma unroll 2
  for (int k4 = 0; k4 < 16; ++k4) {
    float4 za[4];
#pragma unroll
    for (int i = 0; i < 4; ++i) za[i] = *(const float4*)&zl[(n0 + i) * ZS + k4 * 4];
#pragma unroll
    for (int kk = 0; kk < 4; ++kk) {
      const float4 w0 = *(const float4*)&w1l[(k4 * 4 + kk) * 128 + jg * 4];
      const float4 w1 = *(const float4*)&w1l[(k4 * 4 + kk) * 128 + 64 + jg * 4];
#pragma unroll
      for (int i = 0; i < 4; ++i) {
        const float zv = ((const float*)&za[i])[kk];
        acc[i][0] = fmaf(zv, w0.x, acc[i][0]);
        acc[i][1] = fmaf(zv, w0.y, acc[i][1]);
        acc[i][2] = fmaf(zv, w0.z, acc[i][2]);
        acc[i][3] = fmaf(zv, w0.w, acc[i][3]);
        acc[i][4] = fmaf(zv, w1.x, acc[i][4]);
        acc[i][5] = fmaf(zv, w1.y, acc[i][5]);
        acc[i][6] = fmaf(zv, w1.z, acc[i][6]);
        acc[i][7] = fmaf(zv, w1.w, acc[i][7]);
      }
    }
  }
  const float4 av0 = *(const float4*)&a1[jg * 4], av1 = *(const float4*)&a1[64 + jg * 4];
  const float4 cv0 = *(const float4*)&c1p[jg * 4], cv1 = *(const float4*)&c1p[64 + jg * 4];
  __syncthreads();  // zl/w1l reads done; accs in regs
  const int sxor = ng & 7;
#pragma unroll
  for (int i = 0; i < 4; ++i) {
    float4 v0, v1;
    v0.x = fmaxf(fmaf(acc[i][0], av0.x, cv0.x), 0.f);
    v0.y = fmaxf(fmaf(acc[i][1], av0.y, cv0.y), 0.f);
    v0.z = fmaxf(fmaf(acc[i][2], av0.z, cv0.z), 0.f);
    v0.w = fmaxf(fmaf(acc[i][3], av0.w, cv0.w), 0.f);
    v1.x = fmaxf(fmaf(acc[i][4], av1.x, cv1.x), 0.f);
    v1.y = fmaxf(fmaf(acc[i][5], av1.y, cv1.y), 0.f);
    v1.z = fmaxf(fmaf(acc[i][6], av1.z, cv1.z), 0.f);
    v1.w = fmaxf(fmaf(acc[i][7], av1.w, cv1.w), 0.f);
    const int g0 = jg ^ sxor, g1i = 16 + (jg ^ sxor);
    *(float4*)&z1l[(n0 + i) * 128 + g0 * 4] = v0;
    *(float4*)&z1l[(n0 + i) * 128 + g1i * 4] = v1;
  }
  for (int i = tid; i < 2048; i += 256)
    *(float4*)&w2l[i * 4] = *(const float4*)&W2g[i * 4];
  __syncthreads();

  const int jb = (tid & 7) * 8, n0b = (tid >> 3) * 2;
  const float4 b20 = *(const float4*)&b2[jb], b21 = *(const float4*)&b2[jb + 4];
  float accB[2][8];
#pragma unroll
  for (int i = 0; i < 2; ++i) {
    accB[i][0] = b20.x; accB[i][1] = b20.y; accB[i][2] = b20.z; accB[i][3] = b20.w;
    accB[i][4] = b21.x; accB[i][5] = b21.y; accB[i][6] = b21.z; accB[i][7] = b21.w;
  }
#pragma unroll 2
  for (int k4 = 0; k4 < 32; ++k4) {
    float4 zb[2];
#pragma unroll
    for (int i = 0; i < 2; ++i) {
      const int n = n0b + i;
      const int gs = k4 ^ ((n >> 2) & 7);
      zb[i] = *(const float4*)&z1l[n * 128 + gs * 4];
    }
#pragma unroll
    for (int kk = 0; kk < 4; ++kk) {
      const float4 w0 = *(const float4*)&w2l[(k4 * 4 + kk) * 64 + jb];
      const float4 w1 = *(const float4*)&w2l[(k4 * 4 + kk) * 64 + jb + 4];
#pragma unroll
      for (int i = 0; i < 2; ++i) {
        const float zv = ((const float*)&zb[i])[kk];
        accB[i][0] = fmaf(zv, w0.x, accB[i][0]);
        accB[i][1] = fmaf(zv, w0.y, accB[i][1]);
        accB[i][2] = fmaf(zv, w0.z, accB[i][2]);
        accB[i][3] = fmaf(zv, w0.w, accB[i][3]);
        accB[i][4] = fmaf(zv, w1.x, accB[i][4]);
        accB[i][5] = fmaf(zv, w1.y, accB[i][5]);
        accB[i][6] = fmaf(zv, w1.z, accB[i][6]);
        accB[i][7] = fmaf(zv, w1.w, accB[i][7]);
      }
    }
  }
  float sj[8], qj[8];
#pragma unroll
  for (int c = 0; c < 8; ++c) { sj[c] = 0.f; qj[c] = 0.f; }
#pragma unroll
  for (int i = 0; i < 2; ++i) {
    const int n = n0b + i;
    if (n < nlim) {
      float4 o0, o1;
      o0.x = accB[i][0]; o0.y = accB[i][1]; o0.z = accB[i][2]; o0.w = accB[i][3];
      o1.x = accB[i][4]; o1.y = accB[i][5]; o1.z = accB[i][6]; o1.w = accB[i][7];
      *(float4*)&zout[(size_t)(nb + n) * 64 + jb] = o0;
      *(float4*)&zout[(size_t)(nb + n) * 64 + jb + 4] = o1;
#pragma unroll
      for (int c = 0; c < 8; ++c) {
        sj[c] += accB[i][c];
        qj[c] = fmaf(accB[i][c], accB[i][c], qj[c]);
      }
    }
  }
#pragma unroll
  for (int c = 0; c < 8; ++c) {
    atomicAdd(&ss[jb + c], sj[c]);
    atomicAdd(&sq[jb + c], qj[c]);
  }
  __syncthreads();
  if (tid < 64) {
    atomicAdd(&s2[tid], ss[tid]);
    atomicAdd(&q2[tid], sq[tid]);
  }
}

__global__ void k_finalize(const float* __restrict__ sum, const float* __restrict__ sq,
                           const float* __restrict__ g, const float* __restrict__ b,
                           float* __restrict__ a, float* __restrict__ c) {
  int j = threadIdx.x;
  const float inv = 1.0f / (float)N_NODES;
  float m = sum[j] * inv;
  float v = sq[j] * inv - m * m;
  float r = rsqrtf(v + 1e-5f);
  float aa = g[j] * r;
  a[j] = aa;
  c[j] = fmaf(-m, aa, b[j]);
}

// final: bn2 affine (no relu) + mean-pool
__global__ void k_pool(const float* __restrict__ z2, const float* __restrict__ a2,
                       const float* __restrict__ c2, const int* __restrict__ batch,
                       float* __restrict__ pooled, float* __restrict__ cnt) {
  int n = blockIdx.x * 4 + (threadIdx.x >> 6);
  int d = threadIdx.x & 63;
  float v = fmaf(z2[n * 64 + d], a2[d], c2[d]);
  int g = batch[n];
  atomicAdd(&pooled[g * 64 + d], v);
  if (d == 0) atomicAdd(&cnt[g], 1.0f);
}

__global__ void k_div(const float* __restrict__ pooled, const float* __restrict__ cnt,
                      float* __restrict__ out) {
  int g = blockIdx.x, d = threadIdx.x;
  out[g * 64 + d] = pooled[g * 64 + d] / (cnt[g] + 1e-9f);
}

extern "C" void kernel_launch(void* const* d_in, const int* in_sizes, int n_in,
                              void* d_out, int out_size, void* d_ws, size_t ws_size,
                              hipStream_t stream) {
  const int* x = (const int*)d_in[0];
  const int* ea = (const int*)d_in[1];
  const int* ei = (const int*)d_in[2];
  const int* batch = (const int*)d_in[3];
  const float* atom_emb = (const float*)d_in[4];
  const float* bond_emb = (const float*)d_in[5];
  const float* W1 = (const float*)d_in[6];
  const float* g1 = (const float*)d_in[8];
  const float* be1 = (const float*)d_in[9];
  const float* W2 = (const float*)d_in[10];
  const float* b2 = (const float*)d_in[11];
  const float* eps = (const float*)d_in[12];
  const float* bn_g = (const float*)d_in[13];
  const float* bn_b = (const float*)d_in[14];

  float* w = (float*)d_ws;
  float* A = w;                                 // h0, then z2
  float* B = w + (size_t)N_NODES * 64;
  float* stats = B + (size_t)N_NODES * 64;      // 4x(cs|M) = 16640
  float* s2 = stats + 16640;
  float* q2 = stats + 16704;
  float* a1 = stats + 16768;
  float* c1p = stats + 16896;
  float* a2 = stats + 17024;
  float* c2 = stats + 17088;
  float* pooled = stats + 17152;
  float* cnt = pooled + (size_t)NG * 64;
  int* ptr = (int*)(cnt + NG);                  // 100001
  int* deg = ptr + (N_NODES + 1);               // 100000
  unsigned int* csr = (unsigned int*)(deg + N_NODES);  // 1.6M
  int* bs = (int*)(csr + N_EDGES);              // 391

  const int NBLK = (N_NODES + 255) / 256;  // 391
  const int NTILE = (N_NODES + 63) / 64;   // 1563
  const int NPULL = N_NODES / 32;          // 3125 (exact)

  hipMemsetAsync(pooled, 0, (NG * 64 + NG) * sizeof(float), stream);
  hipMemsetAsync(deg, 0, N_NODES * sizeof(int), stream);

  k_atom_embed<<<N_NODES / 4, 256, 0, stream>>>(x, atom_emb, A);

  // CSR build (once; reused across all 4 layers)
  k_hist<<<(N_EDGES + 255) / 256, 256, 0, stream>>>(ei, deg);
  k_scan1<<<NBLK, 256, 0, stream>>>(deg, bs);
  k_scan2<<<1, 512, 0, stream>>>(bs, NBLK);
  k_scan3<<<NBLK, 256, 0, stream>>>(deg, bs, ptr);
  k_fill<<<(N_EDGES + 255) / 256, 256, 0, stream>>>(ei, ea, deg, csr);

  for (int l = 0; l < NL; ++l) {
    hipMemsetAsync(stats, 0, 16768 * sizeof(float), stream);  // cs/M copies + s2/q2
    k_pull<<<NPULL, 256, 0, stream>>>(
        A, csr, ptr, bond_emb + (size_t)l * 1536, a2, c2, eps + l,
        (l > 0) ? 1 : 0, B);
    k_zstats<<<NTILE, 256, 0, stream>>>(B, stats);
    k_fin1<<<1, 128, 0, stream>>>(stats, W1 + (size_t)l * 8192,
                                  g1 + l * 128, be1 + l * 128, a1, c1p);
    k_mm2<<<NTILE, 256, 0, stream>>>(
        B, W1 + (size_t)l * 8192, a1, c1p, W2 + (size_t)l * 8192, b2 + l * 64,
        A, s2, q2);
    k_finalize<<<1, 64, 0, stream>>>(s2, q2, bn_g + l * 64, bn_b + l * 64, a2, c2);
  }
  k_pool<<<N_NODES / 4, 256, 0, stream>>>(A, a2, c2, batch, pooled, cnt);
  k_div<<<NG, 64, 0, stream>>>(pooled, cnt, (float*)d_out);
}

// Round 7
// 1606.497 us; speedup vs baseline: 6.2721x; 1.0599x over previous
//
#include <hip/hip_runtime.h>

#define N_NODES 100000
#define N_EDGES 1600000
#define NL 4
#define NG 1024
#define ZS 68  // LDS z-tile stride (64+4)

// ---------------------------------------------------------------------------
// ws layout (floats):
//   A      @ 0          : N*64   h0 (atom embed); then z2 (in-place reuse)
//   B      @ 6.4M       : N*64   z accumulation (pull out, zstats/mm2 in)
//   stats  @ 12.8M      : 17152  [ 4 x (cs 64 | M 4096)  = 16640
//                                  s2 64 | q2 64 | a1 128 | c1p 128 | a2 64 | c2 64 ]
//   ints   @ ...        : ptr[100001] deg/cursor[100000] csr[1.6M] bs[391]
// ---------------------------------------------------------------------------

__global__ void k_atom_embed(const int* __restrict__ x, const float* __restrict__ emb,
                             float* __restrict__ h) {
  int n = blockIdx.x * 4 + (threadIdx.x >> 6);
  int d = threadIdx.x & 63;
  const int* xr = x + n * 9;
  float acc = 0.f;
#pragma unroll
  for (int c = 0; c < 9; ++c) acc += emb[(c * 100 + xr[c]) * 64 + d];
  h[n * 64 + d] = acc;
}

// ---------------- CSR build (once per call) --------------------------------
__global__ void k_hist(const int* __restrict__ ei, int* __restrict__ deg) {
  int e = blockIdx.x * 256 + threadIdx.x;
  if (e < N_EDGES) atomicAdd(&deg[ei[e]], 1);
}

__global__ void k_scan1(const int* __restrict__ deg, int* __restrict__ bs) {
  __shared__ int s[256];
  int g = blockIdx.x * 256 + threadIdx.x;
  int v = (g < N_NODES) ? deg[g] : 0;
  s[threadIdx.x] = v;
  __syncthreads();
  for (int o = 128; o > 0; o >>= 1) {
    if (threadIdx.x < o) s[threadIdx.x] += s[threadIdx.x + o];
    __syncthreads();
  }
  if (threadIdx.x == 0) bs[blockIdx.x] = s[0];
}

__global__ void k_scan2(int* __restrict__ bs, int nblk) {
  __shared__ int s[512];
  int tid = threadIdx.x;
  int v = (tid < nblk) ? bs[tid] : 0;
  s[tid] = v;
  __syncthreads();
  for (int o = 1; o < 512; o <<= 1) {
    int t = (tid >= o) ? s[tid - o] : 0;
    __syncthreads();
    s[tid] += t;
    __syncthreads();
  }
  if (tid < nblk) bs[tid] = s[tid] - v;  // exclusive
}

__global__ void k_scan3(int* __restrict__ deg, const int* __restrict__ bs,
                        int* __restrict__ ptr) {
  __shared__ int s[256];
  int tid = threadIdx.x;
  int g = blockIdx.x * 256 + tid;
  int v = (g < N_NODES) ? deg[g] : 0;
  s[tid] = v;
  __syncthreads();
  for (int o = 1; o < 256; o <<= 1) {
    int t = (tid >= o) ? s[tid - o] : 0;
    __syncthreads();
    s[tid] += t;
    __syncthreads();
  }
  if (g < N_NODES) {
    int val = bs[blockIdx.x] + s[tid] - v;
    ptr[g] = val;
    deg[g] = val;  // reuse deg as fill cursor
  }
  if (g == 0) ptr[N_NODES] = N_EDGES;
}

__global__ void k_fill(const int* __restrict__ ei, const int* __restrict__ ea,
                       int* __restrict__ cur, unsigned int* __restrict__ csr) {
  int e = blockIdx.x * 256 + threadIdx.x;
  if (e >= N_EDGES) return;
  int s = ei[e];
  unsigned int dst = (unsigned int)ei[N_EDGES + e];
  unsigned int b = (unsigned int)(ea[e * 3] | (ea[e * 3 + 1] << 3) | (ea[e * 3 + 2] << 6));
  int pos = atomicAdd(&cur[s], 1);
  csr[pos] = dst | (b << 17);
}

// ---------------- pull-mode aggregation -------------------------------------
__global__ void __launch_bounds__(256)
k_pull(const float* __restrict__ src, const unsigned int* __restrict__ csr,
       const int* __restrict__ ptr, const float* __restrict__ bond,
       const float* __restrict__ aprev, const float* __restrict__ cprev,
       const float* __restrict__ epsp, int reluf,
       float* __restrict__ z) {
  __shared__ float sb[1536];
  for (int i = threadIdx.x; i < 1536; i += 256) sb[i] = bond[i];
  __syncthreads();
  const int wave = threadIdx.x >> 6, d = threadIdx.x & 63;
  const float ep1 = 1.0f + epsp[0];
  const float aA = reluf ? aprev[d] : 1.0f;
  const float cC = reluf ? cprev[d] : 0.0f;
  const int n0 = blockIdx.x * 32 + wave * 8;
#pragma unroll
  for (int ii = 0; ii < 8; ++ii) {
    int n = n0 + ii;
    int p0 = ptr[n], p1 = ptr[n + 1];
    float own = src[(size_t)n * 64 + d];
    if (reluf) own = fmaxf(fmaf(own, aA, cC), 0.f);
    float acc = ep1 * own;
    for (int base = p0; base < p1; base += 64) {
      int cnt = min(64, p1 - base);
      unsigned int mypk = (d < cnt) ? csr[base + d] : 0u;
      int i = 0;
      for (; i + 4 <= cnt; i += 4) {
        unsigned int pk0 = __shfl(mypk, i), pk1 = __shfl(mypk, i + 1),
                     pk2 = __shfl(mypk, i + 2), pk3 = __shfl(mypk, i + 3);
        float v0 = src[(size_t)(pk0 & 0x1FFFFu) * 64 + d];
        float v1 = src[(size_t)(pk1 & 0x1FFFFu) * 64 + d];
        float v2 = src[(size_t)(pk2 & 0x1FFFFu) * 64 + d];
        float v3 = src[(size_t)(pk3 & 0x1FFFFu) * 64 + d];
        if (reluf) {
          v0 = fmaxf(fmaf(v0, aA, cC), 0.f);
          v1 = fmaxf(fmaf(v1, aA, cC), 0.f);
          v2 = fmaxf(fmaf(v2, aA, cC), 0.f);
          v3 = fmaxf(fmaf(v3, aA, cC), 0.f);
        }
        unsigned int b0 = pk0 >> 17, b1 = pk1 >> 17, b2x = pk2 >> 17, b3 = pk3 >> 17;
        float e0 = sb[(b0 & 7) * 64 + d] + sb[(((b0 >> 3) & 7) + 8) * 64 + d] + sb[((b0 >> 6) + 16) * 64 + d];
        float e1 = sb[(b1 & 7) * 64 + d] + sb[(((b1 >> 3) & 7) + 8) * 64 + d] + sb[((b1 >> 6) + 16) * 64 + d];
        float e2 = sb[(b2x & 7) * 64 + d] + sb[(((b2x >> 3) & 7) + 8) * 64 + d] + sb[((b2x >> 6) + 16) * 64 + d];
        float e3 = sb[(b3 & 7) * 64 + d] + sb[(((b3 >> 3) & 7) + 8) * 64 + d] + sb[((b3 >> 6) + 16) * 64 + d];
        acc += fmaxf(v0 + e0, 0.f);
        acc += fmaxf(v1 + e1, 0.f);
        acc += fmaxf(v2 + e2, 0.f);
        acc += fmaxf(v3 + e3, 0.f);
      }
      for (; i < cnt; ++i) {
        unsigned int pk = __shfl(mypk, i);
        float v = src[(size_t)(pk & 0x1FFFFu) * 64 + d];
        if (reluf) v = fmaxf(fmaf(v, aA, cC), 0.f);
        unsigned int b = pk >> 17;
        float ef = sb[(b & 7) * 64 + d] + sb[(((b >> 3) & 7) + 8) * 64 + d] + sb[((b >> 6) + 16) * 64 + d];
        acc += fmaxf(v + ef, 0.f);
      }
    }
    z[(size_t)n * 64 + d] = acc;
  }
}

// ---------------- BN1 moments: colsum(z), M = z^T z -------------------------
__global__ void __launch_bounds__(256)
k_zstats(const float* __restrict__ z, float* __restrict__ stats) {
  __shared__ __align__(16) float zl[64 * ZS];
  __shared__ float red[256];
  int tid = threadIdx.x;
  int nb = blockIdx.x * 64;
  int nlim = N_NODES - nb;
  for (int i = tid; i < 1024; i += 256) {
    int n = i >> 4, k4 = (i & 15) << 2;
    float4 v = make_float4(0.f, 0.f, 0.f, 0.f);
    if (n < nlim) v = *(const float4*)&z[(size_t)(nb + n) * 64 + k4];
    *(float4*)&zl[n * ZS + k4] = v;
  }
  __syncthreads();
  float* copy = stats + (blockIdx.x & 3) * 4160;  // [cs 64 | M 4096]
  {
    int wave = tid >> 6, d = tid & 63;
    float s = 0.f;
#pragma unroll
    for (int ii = 0; ii < 16; ++ii) s += zl[(wave * 16 + ii) * ZS + d];
    red[tid] = s;
    __syncthreads();
    if (tid < 64)
      atomicAdd(&copy[tid], red[tid] + red[tid + 64] + red[tid + 128] + red[tid + 192]);
  }
  const int ar = (tid >> 4) * 4, bc = (tid & 15) * 4;
  float m00 = 0.f, m01 = 0.f, m02 = 0.f, m03 = 0.f;
  float m10 = 0.f, m11 = 0.f, m12 = 0.f, m13 = 0.f;
  float m20 = 0.f, m21 = 0.f, m22 = 0.f, m23 = 0.f;
  float m30 = 0.f, m31 = 0.f, m32 = 0.f, m33 = 0.f;
#pragma unroll 4
  for (int n = 0; n < 64; ++n) {
    const float4 a = *(const float4*)&zl[n * ZS + ar];
    const float4 b = *(const float4*)&zl[n * ZS + bc];
    m00 = fmaf(a.x, b.x, m00); m01 = fmaf(a.x, b.y, m01); m02 = fmaf(a.x, b.z, m02); m03 = fmaf(a.x, b.w, m03);
    m10 = fmaf(a.y, b.x, m10); m11 = fmaf(a.y, b.y, m11); m12 = fmaf(a.y, b.z, m12); m13 = fmaf(a.y, b.w, m13);
    m20 = fmaf(a.z, b.x, m20); m21 = fmaf(a.z, b.y, m21); m22 = fmaf(a.z, b.z, m22); m23 = fmaf(a.z, b.w, m23);
    m30 = fmaf(a.w, b.x, m30); m31 = fmaf(a.w, b.y, m31); m32 = fmaf(a.w, b.z, m32); m33 = fmaf(a.w, b.w, m33);
  }
  float* M = copy + 64;
  atomicAdd(&M[(ar + 0) * 64 + bc + 0], m00); atomicAdd(&M[(ar + 0) * 64 + bc + 1], m01);
  atomicAdd(&M[(ar + 0) * 64 + bc + 2], m02); atomicAdd(&M[(ar + 0) * 64 + bc + 3], m03);
  atomicAdd(&M[(ar + 1) * 64 + bc + 0], m10); atomicAdd(&M[(ar + 1) * 64 + bc + 1], m11);
  atomicAdd(&M[(ar + 1) * 64 + bc + 2], m12); atomicAdd(&M[(ar + 1) * 64 + bc + 3], m13);
  atomicAdd(&M[(ar + 2) * 64 + bc + 0], m20); atomicAdd(&M[(ar + 2) * 64 + bc + 1], m21);
  atomicAdd(&M[(ar + 2) * 64 + bc + 2], m22); atomicAdd(&M[(ar + 2) * 64 + bc + 3], m23);
  atomicAdd(&M[(ar + 3) * 64 + bc + 0], m30); atomicAdd(&M[(ar + 3) * 64 + bc + 1], m31);
  atomicAdd(&M[(ar + 3) * 64 + bc + 2], m32); atomicAdd(&M[(ar + 3) * 64 + bc + 3], m33);
}

// BN1 params from moments (sums the 4 replicated copies)
__global__ void __launch_bounds__(128, 1)
k_fin1(const float* __restrict__ stats,
       const float* __restrict__ W1, const float* __restrict__ g1,
       const float* __restrict__ be1,
       float* __restrict__ a1, float* __restrict__ c1p) {
  __shared__ float Ml[4096];
  __shared__ float csl[64];
  int j = threadIdx.x;
  for (int i = j; i < 4096; i += 128)
    Ml[i] = stats[64 + i] + stats[4160 + 64 + i] + stats[8320 + 64 + i] + stats[12480 + 64 + i];
  if (j < 64) csl[j] = stats[j] + stats[4160 + j] + stats[8320 + j] + stats[12480 + j];
  __syncthreads();
  float wcol[64];
#pragma unroll
  for (int k = 0; k < 64; ++k) wcol[k] = W1[k * 128 + j];
  float m0 = 0.f;
#pragma unroll
  for (int k = 0; k < 64; ++k) m0 = fmaf(csl[k], wcol[k], m0);
  m0 *= (1.0f / (float)N_NODES);
  float q = 0.f;
  for (int ka = 0; ka < 64; ++ka) {
    const float4* mr = (const float4*)&Ml[ka * 64];
    float t = 0.f;
#pragma unroll
    for (int kb = 0; kb < 16; ++kb) {
      float4 m = mr[kb];
      t = fmaf(m.x, wcol[kb * 4 + 0], t);
      t = fmaf(m.y, wcol[kb * 4 + 1], t);
      t = fmaf(m.z, wcol[kb * 4 + 2], t);
      t = fmaf(m.w, wcol[kb * 4 + 3], t);
    }
    q = fmaf(wcol[ka], t, q);
  }
  float var = q * (1.0f / (float)N_NODES) - m0 * m0;
  float r = rsqrtf(var + 1e-5f);
  float A = g1[j] * r;
  a1[j] = A;
  c1p[j] = fmaf(-m0, A, be1[j]);
}

// fused MLP: z@W1 -> bn1 affine+relu -> LDS (swizzled) -> @W2 -> z2 + stats2
__global__ void __launch_bounds__(256, 2)
k_mm2(const float* __restrict__ z, const float* __restrict__ W1g,
      const float* __restrict__ a1, const float* __restrict__ c1p,
      const float* __restrict__ W2g, const float* __restrict__ b2,
      float* __restrict__ zout, float* __restrict__ s2, float* __restrict__ q2) {
  __shared__ __align__(16) float sm[16512];
  float* zl = sm;            // [64][68] phase A
  float* w1l = sm + 4352;    // [64][128]
  float* z1l = sm;           // [64][32 granules] phase B (overlays)
  float* w2l = sm + 8192;    // [128][64]
  float* ss = sm + 16384;
  float* sq = sm + 16448;
  int tid = threadIdx.x;
  int nb = blockIdx.x * 64;
  int nlim = N_NODES - nb;
  if (tid < 128) sm[16384 + tid] = 0.f;
  for (int i = tid; i < 1024; i += 256) {
    int n = i >> 4, k4 = (i & 15) << 2;
    float4 v = make_float4(0.f, 0.f, 0.f, 0.f);
    if (n < nlim) v = *(const float4*)&z[(size_t)(nb + n) * 64 + k4];
    *(float4*)&zl[n * ZS + k4] = v;
  }
  for (int i = tid; i < 2048; i += 256)
    *(float4*)&w1l[i * 4] = *(const float4*)&W1g[i * 4];
  __syncthreads();

  const int jg = tid & 15, ng = tid >> 4;
  const int n0 = ng * 4;
  float acc[4][8];
#pragma unroll
  for (int i = 0; i < 4; ++i)
#pragma unroll
    for (int c = 0; c < 8; ++c) acc[i][c] = 0.f;
#pragma unroll 2
  for (int k4 = 0; k4 < 16; ++k4) {
    float4 za[4];
#pragma unroll
    for (int i = 0; i < 4; ++i) za[i] = *(const float4*)&zl[(n0 + i) * ZS + k4 * 4];
#pragma unroll
    for (int kk = 0; kk < 4; ++kk) {
      const float4 w0 = *(const float4*)&w1l[(k4 * 4 + kk) * 128 + jg * 4];
      const float4 w1 = *(const float4*)&w1l[(k4 * 4 + kk) * 128 + 64 + jg * 4];
#pragma unroll
      for (int i = 0; i < 4; ++i) {
        const float zv = ((const float*)&za[i])[kk];
        acc[i][0] = fmaf(zv, w0.x, acc[i][0]);
        acc[i][1] = fmaf(zv, w0.y, acc[i][1]);
        acc[i][2] = fmaf(zv, w0.z, acc[i][2]);
        acc[i][3] = fmaf(zv, w0.w, acc[i][3]);
        acc[i][4] = fmaf(zv, w1.x, acc[i][4]);
        acc[i][5] = fmaf(zv, w1.y, acc[i][5]);
        acc[i][6] = fmaf(zv, w1.z, acc[i][6]);
        acc[i][7] = fmaf(zv, w1.w, acc[i][7]);
      }
    }
  }
  const float4 av0 = *(const float4*)&a1[jg * 4], av1 = *(const float4*)&a1[64 + jg * 4];
  const float4 cv0 = *(const float4*)&c1p[jg * 4], cv1 = *(const float4*)&c1p[64 + jg * 4];
  __syncthreads();  // zl/w1l reads done; accs in regs
  const int sxor = ng & 7;
#pragma unroll
  for (int i = 0; i < 4; ++i) {
    float4 v0, v1;
    v0.x = fmaxf(fmaf(acc[i][0], av0.x, cv0.x), 0.f);
    v0.y = fmaxf(fmaf(acc[i][1], av0.y, cv0.y), 0.f);
    v0.z = fmaxf(fmaf(acc[i][2], av0.z, cv0.z), 0.f);
    v0.w = fmaxf(fmaf(acc[i][3], av0.w, cv0.w), 0.f);
    v1.x = fmaxf(fmaf(acc[i][4], av1.x, cv1.x), 0.f);
    v1.y = fmaxf(fmaf(acc[i][5], av1.y, cv1.y), 0.f);
    v1.z = fmaxf(fmaf(acc[i][6], av1.z, cv1.z), 0.f);
    v1.w = fmaxf(fmaf(acc[i][7], av1.w, cv1.w), 0.f);
    const int g0 = jg ^ sxor, g1i = 16 + (jg ^ sxor);
    *(float4*)&z1l[(n0 + i) * 128 + g0 * 4] = v0;
    *(float4*)&z1l[(n0 + i) * 128 + g1i * 4] = v1;
  }
  for (int i = tid; i < 2048; i += 256)
    *(float4*)&w2l[i * 4] = *(const float4*)&W2g[i * 4];
  __syncthreads();

  const int jb = (tid & 7) * 8, n0b = (tid >> 3) * 2;
  const float4 b20 = *(const float4*)&b2[jb], b21 = *(const float4*)&b2[jb + 4];
  float accB[2][8];
#pragma unroll
  for (int i = 0; i < 2; ++i) {
    accB[i][0] = b20.x; accB[i][1] = b20.y; accB[i][2] = b20.z; accB[i][3] = b20.w;
    accB[i][4] = b21.x; accB[i][5] = b21.y; accB[i][6] = b21.z; accB[i][7] = b21.w;
  }
#pragma unroll 2
  for (int k4 = 0; k4 < 32; ++k4) {
    float4 zb[2];
#pragma unroll
    for (int i = 0; i < 2; ++i) {
      const int n = n0b + i;
      const int gs = k4 ^ ((n >> 2) & 7);
      zb[i] = *(const float4*)&z1l[n * 128 + gs * 4];
    }
#pragma unroll
    for (int kk = 0; kk < 4; ++kk) {
      const float4 w0 = *(const float4*)&w2l[(k4 * 4 + kk) * 64 + jb];
      const float4 w1 = *(const float4*)&w2l[(k4 * 4 + kk) * 64 + jb + 4];
#pragma unroll
      for (int i = 0; i < 2; ++i) {
        const float zv = ((const float*)&zb[i])[kk];
        accB[i][0] = fmaf(zv, w0.x, accB[i][0]);
        accB[i][1] = fmaf(zv, w0.y, accB[i][1]);
        accB[i][2] = fmaf(zv, w0.z, accB[i][2]);
        accB[i][3] = fmaf(zv, w0.w, accB[i][3]);
        accB[i][4] = fmaf(zv, w1.x, accB[i][4]);
        accB[i][5] = fmaf(zv, w1.y, accB[i][5]);
        accB[i][6] = fmaf(zv, w1.z, accB[i][6]);
        accB[i][7] = fmaf(zv, w1.w, accB[i][7]);
      }
    }
  }
  float sj[8], qj[8];
#pragma unroll
  for (int c = 0; c < 8; ++c) { sj[c] = 0.f; qj[c] = 0.f; }
#pragma unroll
  for (int i = 0; i < 2; ++i) {
    const int n = n0b + i;
    if (n < nlim) {
      float4 o0, o1;
      o0.x = accB[i][0]; o0.y = accB[i][1]; o0.z = accB[i][2]; o0.w = accB[i][3];
      o1.x = accB[i][4]; o1.y = accB[i][5]; o1.z = accB[i][6]; o1.w = accB[i][7];
      *(float4*)&zout[(size_t)(nb + n) * 64 + jb] = o0;
      *(float4*)&zout[(size_t)(nb + n) * 64 + jb + 4] = o1;
#pragma unroll
      for (int c = 0; c < 8; ++c) {
        sj[c] += accB[i][c];
        qj[c] = fmaf(accB[i][c], accB[i][c], qj[c]);
      }
    }
  }
#pragma unroll
  for (int c = 0; c < 8; ++c) {
    atomicAdd(&ss[jb + c], sj[c]);
    atomicAdd(&sq[jb + c], qj[c]);
  }
  __syncthreads();
  if (tid < 64) {
    atomicAdd(&s2[tid], ss[tid]);
    atomicAdd(&q2[tid], sq[tid]);
  }
}

__global__ void k_finalize(const float* __restrict__ sum, const float* __restrict__ sq,
                           const float* __restrict__ g, const float* __restrict__ b,
                           float* __restrict__ a, float* __restrict__ c) {
  int j = threadIdx.x;
  const float inv = 1.0f / (float)N_NODES;
  float m = sum[j] * inv;
  float v = sq[j] * inv - m * m;
  float r = rsqrtf(v + 1e-5f);
  float aa = g[j] * r;
  a[j] = aa;
  c[j] = fmaf(-m, aa, b[j]);
}

// ---------------- pool: batch is SORTED -> one wave per graph, zero atomics.
// Each lane binary-searches [lower_bound(g), lower_bound(g+1)) (wave-uniform
// broadcast loads), then lane d sums z2[n*64+d] over the contiguous range
// (coalesced 256B lines). BN2 affine hoisted: out=(a2*S + cnt*c2)/(cnt+eps).
// (round-6: atomicAdd into pooled[] with ~98-node same-address runs ->
//  6.4M serialized atomics, 133us, VALUBusy 1.9%)
__global__ void __launch_bounds__(256)
k_pool(const float* __restrict__ z2, const float* __restrict__ a2,
       const float* __restrict__ c2, const int* __restrict__ batch,
       float* __restrict__ out) {
  int g = blockIdx.x * 4 + (threadIdx.x >> 6);
  int d = threadIdx.x & 63;
  int a = 0, b = N_NODES;
  while (a < b) { int m = (a + b) >> 1; if (batch[m] < g) a = m + 1; else b = m; }
  const int lo = a;
  b = N_NODES;
  while (a < b) { int m = (a + b) >> 1; if (batch[m] < g + 1) a = m + 1; else b = m; }
  const int hi = a;
  float s0 = 0.f, s1 = 0.f, s2 = 0.f, s3 = 0.f;
  int n = lo;
  for (; n + 4 <= hi; n += 4) {
    s0 += z2[(size_t)(n + 0) * 64 + d];
    s1 += z2[(size_t)(n + 1) * 64 + d];
    s2 += z2[(size_t)(n + 2) * 64 + d];
    s3 += z2[(size_t)(n + 3) * 64 + d];
  }
  for (; n < hi; ++n) s0 += z2[(size_t)n * 64 + d];
  float S = (s0 + s1) + (s2 + s3);
  float cntf = (float)(hi - lo);
  out[g * 64 + d] = fmaf(S, a2[d], cntf * c2[d]) / (cntf + 1e-9f);
}

extern "C" void kernel_launch(void* const* d_in, const int* in_sizes, int n_in,
                              void* d_out, int out_size, void* d_ws, size_t ws_size,
                              hipStream_t stream) {
  const int* x = (const int*)d_in[0];
  const int* ea = (const int*)d_in[1];
  const int* ei = (const int*)d_in[2];
  const int* batch = (const int*)d_in[3];
  const float* atom_emb = (const float*)d_in[4];
  const float* bond_emb = (const float*)d_in[5];
  const float* W1 = (const float*)d_in[6];
  const float* g1 = (const float*)d_in[8];
  const float* be1 = (const float*)d_in[9];
  const float* W2 = (const float*)d_in[10];
  const float* b2 = (const float*)d_in[11];
  const float* eps = (const float*)d_in[12];
  const float* bn_g = (const float*)d_in[13];
  const float* bn_b = (const float*)d_in[14];

  float* w = (float*)d_ws;
  float* A = w;                                 // h0, then z2
  float* B = w + (size_t)N_NODES * 64;
  float* stats = B + (size_t)N_NODES * 64;      // 4x(cs|M) = 16640
  float* s2 = stats + 16640;
  float* q2 = stats + 16704;
  float* a1 = stats + 16768;
  float* c1p = stats + 16896;
  float* a2 = stats + 17024;
  float* c2 = stats + 17088;
  int* ptr = (int*)(stats + 17152);             // 100001
  int* deg = ptr + (N_NODES + 1);               // 100000
  unsigned int* csr = (unsigned int*)(deg + N_NODES);  // 1.6M
  int* bs = (int*)(csr + N_EDGES);              // 391

  const int NBLK = (N_NODES + 255) / 256;  // 391
  const int NTILE = (N_NODES + 63) / 64;   // 1563
  const int NPULL = N_NODES / 32;          // 3125 (exact)

  hipMemsetAsync(deg, 0, N_NODES * sizeof(int), stream);

  k_atom_embed<<<N_NODES / 4, 256, 0, stream>>>(x, atom_emb, A);

  // CSR build (once; reused across all 4 layers)
  k_hist<<<(N_EDGES + 255) / 256, 256, 0, stream>>>(ei, deg);
  k_scan1<<<NBLK, 256, 0, stream>>>(deg, bs);
  k_scan2<<<1, 512, 0, stream>>>(bs, NBLK);
  k_scan3<<<NBLK, 256, 0, stream>>>(deg, bs, ptr);
  k_fill<<<(N_EDGES + 255) / 256, 256, 0, stream>>>(ei, ea, deg, csr);

  for (int l = 0; l < NL; ++l) {
    hipMemsetAsync(stats, 0, 16768 * sizeof(float), stream);  // cs/M copies + s2/q2
    k_pull<<<NPULL, 256, 0, stream>>>(
        A, csr, ptr, bond_emb + (size_t)l * 1536, a2, c2, eps + l,
        (l > 0) ? 1 : 0, B);
    k_zstats<<<NTILE, 256, 0, stream>>>(B, stats);
    k_fin1<<<1, 128, 0, stream>>>(stats, W1 + (size_t)l * 8192,
                                  g1 + l * 128, be1 + l * 128, a1, c1p);
    k_mm2<<<NTILE, 256, 0, stream>>>(
        B, W1 + (size_t)l * 8192, a1, c1p, W2 + (size_t)l * 8192, b2 + l * 64,
        A, s2, q2);
    k_finalize<<<1, 64, 0, stream>>>(s2, q2, bn_g + l * 64, bn_b + l * 64, a2, c2);
  }
  k_pool<<<NG / 4, 256, 0, stream>>>(A, a2, c2, batch, (float*)d_out);
}

// Round 8
// 1297.606 us; speedup vs baseline: 7.7652x; 1.2380x over previous
//
#include <hip/hip_runtime.h>

#define N_NODES 100000
#define N_EDGES 1600000
#define NL 4
#define NG 1024
#define ZS 68  // LDS z-tile stride (64+4)

// ---------------------------------------------------------------------------
// ws layout (floats):
//   A      @ 0          : N*64   h0 (atom embed); then z2 (in-place reuse)
//   B      @ 6.4M       : N*64   z accumulation (pull out, zstats/mm2 in)
//   stats  @ 12.8M      : 17152  [ 4 x (cs 64 | M 4096)  = 16640
//                                  s2 64 | q2 64 | a1 128 | c1p 128 | a2 64 | c2 64 ]
//   ints   @ ...        : ptr[100001] deg/cursor[100000] csr[1.6M] bs[391]
// ---------------------------------------------------------------------------

__global__ void k_atom_embed(const int* __restrict__ x, const float* __restrict__ emb,
                             float* __restrict__ h) {
  int n = blockIdx.x * 4 + (threadIdx.x >> 6);
  int d = threadIdx.x & 63;
  const int* xr = x + n * 9;
  float acc = 0.f;
#pragma unroll
  for (int c = 0; c < 9; ++c) acc += emb[(c * 100 + xr[c]) * 64 + d];
  h[n * 64 + d] = acc;
}

// ---------------- CSR build (once per call) --------------------------------
__global__ void k_hist(const int* __restrict__ ei, int* __restrict__ deg) {
  int e = blockIdx.x * 256 + threadIdx.x;
  if (e < N_EDGES) atomicAdd(&deg[ei[e]], 1);
}

__global__ void k_scan1(const int* __restrict__ deg, int* __restrict__ bs) {
  __shared__ int s[256];
  int g = blockIdx.x * 256 + threadIdx.x;
  int v = (g < N_NODES) ? deg[g] : 0;
  s[threadIdx.x] = v;
  __syncthreads();
  for (int o = 128; o > 0; o >>= 1) {
    if (threadIdx.x < o) s[threadIdx.x] += s[threadIdx.x + o];
    __syncthreads();
  }
  if (threadIdx.x == 0) bs[blockIdx.x] = s[0];
}

__global__ void k_scan2(int* __restrict__ bs, int nblk) {
  __shared__ int s[512];
  int tid = threadIdx.x;
  int v = (tid < nblk) ? bs[tid] : 0;
  s[tid] = v;
  __syncthreads();
  for (int o = 1; o < 512; o <<= 1) {
    int t = (tid >= o) ? s[tid - o] : 0;
    __syncthreads();
    s[tid] += t;
    __syncthreads();
  }
  if (tid < nblk) bs[tid] = s[tid] - v;  // exclusive
}

__global__ void k_scan3(int* __restrict__ deg, const int* __restrict__ bs,
                        int* __restrict__ ptr) {
  __shared__ int s[256];
  int tid = threadIdx.x;
  int g = blockIdx.x * 256 + tid;
  int v = (g < N_NODES) ? deg[g] : 0;
  s[tid] = v;
  __syncthreads();
  for (int o = 1; o < 256; o <<= 1) {
    int t = (tid >= o) ? s[tid - o] : 0;
    __syncthreads();
    s[tid] += t;
    __syncthreads();
  }
  if (g < N_NODES) {
    int val = bs[blockIdx.x] + s[tid] - v;
    ptr[g] = val;
    deg[g] = val;  // reuse deg as fill cursor
  }
  if (g == 0) ptr[N_NODES] = N_EDGES;
}

__global__ void k_fill(const int* __restrict__ ei, const int* __restrict__ ea,
                       int* __restrict__ cur, unsigned int* __restrict__ csr) {
  int e = blockIdx.x * 256 + threadIdx.x;
  if (e >= N_EDGES) return;
  int s = ei[e];
  unsigned int dst = (unsigned int)ei[N_EDGES + e];
  unsigned int b = (unsigned int)(ea[e * 3] | (ea[e * 3 + 1] << 3) | (ea[e * 3 + 2] << 6));
  int pos = atomicAdd(&cur[s], 1);
  csr[pos] = dst | (b << 17);
}

// ---------------- pull-mode aggregation -------------------------------------
// Block 0 additionally zeroes the stats accumulators (cs/M copies + s2/q2) for
// this layer -- pull completes before zstats/mm2 read them (kernel boundary),
// and a2/c2 (offsets >= 17024) are not touched.
__global__ void __launch_bounds__(256)
k_pull(const float* __restrict__ src, const unsigned int* __restrict__ csr,
       const int* __restrict__ ptr, const float* __restrict__ bond,
       const float* __restrict__ aprev, const float* __restrict__ cprev,
       const float* __restrict__ epsp, int reluf,
       float* __restrict__ z, float* __restrict__ stats0) {
  __shared__ float sb[1536];
  for (int i = threadIdx.x; i < 1536; i += 256) sb[i] = bond[i];
  if (blockIdx.x == 0)
    for (int i = threadIdx.x; i < 16768; i += 256) stats0[i] = 0.f;
  __syncthreads();
  const int wave = threadIdx.x >> 6, d = threadIdx.x & 63;
  const float ep1 = 1.0f + epsp[0];
  const float aA = reluf ? aprev[d] : 1.0f;
  const float cC = reluf ? cprev[d] : 0.0f;
  const int n0 = blockIdx.x * 32 + wave * 8;
#pragma unroll
  for (int ii = 0; ii < 8; ++ii) {
    int n = n0 + ii;
    int p0 = ptr[n], p1 = ptr[n + 1];
    float own = src[(size_t)n * 64 + d];
    if (reluf) own = fmaxf(fmaf(own, aA, cC), 0.f);
    float acc = ep1 * own;
    for (int base = p0; base < p1; base += 64) {
      int cnt = min(64, p1 - base);
      unsigned int mypk = (d < cnt) ? csr[base + d] : 0u;
      int i = 0;
      for (; i + 4 <= cnt; i += 4) {
        unsigned int pk0 = __shfl(mypk, i), pk1 = __shfl(mypk, i + 1),
                     pk2 = __shfl(mypk, i + 2), pk3 = __shfl(mypk, i + 3);
        float v0 = src[(size_t)(pk0 & 0x1FFFFu) * 64 + d];
        float v1 = src[(size_t)(pk1 & 0x1FFFFu) * 64 + d];
        float v2 = src[(size_t)(pk2 & 0x1FFFFu) * 64 + d];
        float v3 = src[(size_t)(pk3 & 0x1FFFFu) * 64 + d];
        if (reluf) {
          v0 = fmaxf(fmaf(v0, aA, cC), 0.f);
          v1 = fmaxf(fmaf(v1, aA, cC), 0.f);
          v2 = fmaxf(fmaf(v2, aA, cC), 0.f);
          v3 = fmaxf(fmaf(v3, aA, cC), 0.f);
        }
        unsigned int b0 = pk0 >> 17, b1 = pk1 >> 17, b2x = pk2 >> 17, b3 = pk3 >> 17;
        float e0 = sb[(b0 & 7) * 64 + d] + sb[(((b0 >> 3) & 7) + 8) * 64 + d] + sb[((b0 >> 6) + 16) * 64 + d];
        float e1 = sb[(b1 & 7) * 64 + d] + sb[(((b1 >> 3) & 7) + 8) * 64 + d] + sb[((b1 >> 6) + 16) * 64 + d];
        float e2 = sb[(b2x & 7) * 64 + d] + sb[(((b2x >> 3) & 7) + 8) * 64 + d] + sb[((b2x >> 6) + 16) * 64 + d];
        float e3 = sb[(b3 & 7) * 64 + d] + sb[(((b3 >> 3) & 7) + 8) * 64 + d] + sb[((b3 >> 6) + 16) * 64 + d];
        acc += fmaxf(v0 + e0, 0.f);
        acc += fmaxf(v1 + e1, 0.f);
        acc += fmaxf(v2 + e2, 0.f);
        acc += fmaxf(v3 + e3, 0.f);
      }
      for (; i < cnt; ++i) {
        unsigned int pk = __shfl(mypk, i);
        float v = src[(size_t)(pk & 0x1FFFFu) * 64 + d];
        if (reluf) v = fmaxf(fmaf(v, aA, cC), 0.f);
        unsigned int b = pk >> 17;
        float ef = sb[(b & 7) * 64 + d] + sb[(((b >> 3) & 7) + 8) * 64 + d] + sb[((b >> 6) + 16) * 64 + d];
        acc += fmaxf(v + ef, 0.f);
      }
    }
    z[(size_t)n * 64 + d] = acc;
  }
}

// ---------------- BN1 moments: colsum(z), M = z^T z -------------------------
// 4 tiles (256 nodes) per block; colsum + 4x4 M-subtile accumulate in REGISTERS
// across tiles; the 4160 global atomics issue ONCE per block (round-7: 1563
// blocks x 4160 atomics = 100 MB fabric writes = the whole 129us).
__global__ void __launch_bounds__(256)
k_zstats(const float* __restrict__ z, float* __restrict__ stats) {
  __shared__ __align__(16) float zl[64 * ZS];
  __shared__ float red[256];
  const int tid = threadIdx.x;
  const int wave = tid >> 6, d = tid & 63;
  const int ar = (tid >> 4) * 4, bc = (tid & 15) * 4;
  float accS = 0.f;
  float m00 = 0.f, m01 = 0.f, m02 = 0.f, m03 = 0.f;
  float m10 = 0.f, m11 = 0.f, m12 = 0.f, m13 = 0.f;
  float m20 = 0.f, m21 = 0.f, m22 = 0.f, m23 = 0.f;
  float m30 = 0.f, m31 = 0.f, m32 = 0.f, m33 = 0.f;
  for (int t = 0; t < 4; ++t) {
    const int nb = (blockIdx.x * 4 + t) * 64;
    const int nlim = N_NODES - nb;
    __syncthreads();  // previous tile's reads complete before overwrite
    for (int i = tid; i < 1024; i += 256) {
      int n = i >> 4, k4 = (i & 15) << 2;
      float4 v = make_float4(0.f, 0.f, 0.f, 0.f);
      if (n < nlim) v = *(const float4*)&z[(size_t)(nb + n) * 64 + k4];
      *(float4*)&zl[n * ZS + k4] = v;
    }
    __syncthreads();
#pragma unroll
    for (int ii = 0; ii < 16; ++ii) accS += zl[(wave * 16 + ii) * ZS + d];
#pragma unroll 4
    for (int n = 0; n < 64; ++n) {
      const float4 a = *(const float4*)&zl[n * ZS + ar];
      const float4 b = *(const float4*)&zl[n * ZS + bc];
      m00 = fmaf(a.x, b.x, m00); m01 = fmaf(a.x, b.y, m01); m02 = fmaf(a.x, b.z, m02); m03 = fmaf(a.x, b.w, m03);
      m10 = fmaf(a.y, b.x, m10); m11 = fmaf(a.y, b.y, m11); m12 = fmaf(a.y, b.z, m12); m13 = fmaf(a.y, b.w, m13);
      m20 = fmaf(a.z, b.x, m20); m21 = fmaf(a.z, b.y, m21); m22 = fmaf(a.z, b.z, m22); m23 = fmaf(a.z, b.w, m23);
      m30 = fmaf(a.w, b.x, m30); m31 = fmaf(a.w, b.y, m31); m32 = fmaf(a.w, b.z, m32); m33 = fmaf(a.w, b.w, m33);
    }
  }
  float* copy = stats + (blockIdx.x & 3) * 4160;  // [cs 64 | M 4096]
  red[tid] = accS;
  __syncthreads();
  if (tid < 64)
    atomicAdd(&copy[tid], red[tid] + red[tid + 64] + red[tid + 128] + red[tid + 192]);
  float* M = copy + 64;
  atomicAdd(&M[(ar + 0) * 64 + bc + 0], m00); atomicAdd(&M[(ar + 0) * 64 + bc + 1], m01);
  atomicAdd(&M[(ar + 0) * 64 + bc + 2], m02); atomicAdd(&M[(ar + 0) * 64 + bc + 3], m03);
  atomicAdd(&M[(ar + 1) * 64 + bc + 0], m10); atomicAdd(&M[(ar + 1) * 64 + bc + 1], m11);
  atomicAdd(&M[(ar + 1) * 64 + bc + 2], m12); atomicAdd(&M[(ar + 1) * 64 + bc + 3], m13);
  atomicAdd(&M[(ar + 2) * 64 + bc + 0], m20); atomicAdd(&M[(ar + 2) * 64 + bc + 1], m21);
  atomicAdd(&M[(ar + 2) * 64 + bc + 2], m22); atomicAdd(&M[(ar + 2) * 64 + bc + 3], m23);
  atomicAdd(&M[(ar + 3) * 64 + bc + 0], m30); atomicAdd(&M[(ar + 3) * 64 + bc + 1], m31);
  atomicAdd(&M[(ar + 3) * 64 + bc + 2], m32); atomicAdd(&M[(ar + 3) * 64 + bc + 3], m33);
}

// BN1 params from moments (sums the 4 replicated copies)
__global__ void __launch_bounds__(128, 1)
k_fin1(const float* __restrict__ stats,
       const float* __restrict__ W1, const float* __restrict__ g1,
       const float* __restrict__ be1,
       float* __restrict__ a1, float* __restrict__ c1p) {
  __shared__ float Ml[4096];
  __shared__ float csl[64];
  int j = threadIdx.x;
  for (int i = j; i < 4096; i += 128)
    Ml[i] = stats[64 + i] + stats[4160 + 64 + i] + stats[8320 + 64 + i] + stats[12480 + 64 + i];
  if (j < 64) csl[j] = stats[j] + stats[4160 + j] + stats[8320 + j] + stats[12480 + j];
  __syncthreads();
  float wcol[64];
#pragma unroll
  for (int k = 0; k < 64; ++k) wcol[k] = W1[k * 128 + j];
  float m0 = 0.f;
#pragma unroll
  for (int k = 0; k < 64; ++k) m0 = fmaf(csl[k], wcol[k], m0);
  m0 *= (1.0f / (float)N_NODES);
  float q = 0.f;
  for (int ka = 0; ka < 64; ++ka) {
    const float4* mr = (const float4*)&Ml[ka * 64];
    float t = 0.f;
#pragma unroll
    for (int kb = 0; kb < 16; ++kb) {
      float4 m = mr[kb];
      t = fmaf(m.x, wcol[kb * 4 + 0], t);
      t = fmaf(m.y, wcol[kb * 4 + 1], t);
      t = fmaf(m.z, wcol[kb * 4 + 2], t);
      t = fmaf(m.w, wcol[kb * 4 + 3], t);
    }
    q = fmaf(wcol[ka], t, q);
  }
  float var = q * (1.0f / (float)N_NODES) - m0 * m0;
  float r = rsqrtf(var + 1e-5f);
  float A = g1[j] * r;
  a1[j] = A;
  c1p[j] = fmaf(-m0, A, be1[j]);
}

// fused MLP: z@W1 -> bn1 affine+relu -> LDS (swizzled) -> @W2 -> z2 + stats2
__global__ void __launch_bounds__(256, 2)
k_mm2(const float* __restrict__ z, const float* __restrict__ W1g,
      const float* __restrict__ a1, const float* __restrict__ c1p,
      const float* __restrict__ W2g, const float* __restrict__ b2,
      float* __restrict__ zout, float* __restrict__ s2, float* __restrict__ q2) {
  __shared__ __align__(16) float sm[16512];
  float* zl = sm;            // [64][68] phase A
  float* w1l = sm + 4352;    // [64][128]
  float* z1l = sm;           // [64][32 granules] phase B (overlays)
  float* w2l = sm + 8192;    // [128][64]
  float* ss = sm + 16384;
  float* sq = sm + 16448;
  int tid = threadIdx.x;
  int nb = blockIdx.x * 64;
  int nlim = N_NODES - nb;
  if (tid < 128) sm[16384 + tid] = 0.f;
  for (int i = tid; i < 1024; i += 256) {
    int n = i >> 4, k4 = (i & 15) << 2;
    float4 v = make_float4(0.f, 0.f, 0.f, 0.f);
    if (n < nlim) v = *(const float4*)&z[(size_t)(nb + n) * 64 + k4];
    *(float4*)&zl[n * ZS + k4] = v;
  }
  for (int i = tid; i < 2048; i += 256)
    *(float4*)&w1l[i * 4] = *(const float4*)&W1g[i * 4];
  __syncthreads();

  const int jg = tid & 15, ng = tid >> 4;
  const int n0 = ng * 4;
  float acc[4][8];
#pragma unroll
  for (int i = 0; i < 4; ++i)
#pragma unroll
    for (int c = 0; c < 8; ++c) acc[i][c] = 0.f;
#pragma unroll 2
  for (int k4 = 0; k4 < 16; ++k4) {
    float4 za[4];
#pragma unroll
    for (int i = 0; i < 4; ++i) za[i] = *(const float4*)&zl[(n0 + i) * ZS + k4 * 4];
#pragma unroll
    for (int kk = 0; kk < 4; ++kk) {
      const float4 w0 = *(const float4*)&w1l[(k4 * 4 + kk) * 128 + jg * 4];
      const float4 w1 = *(const float4*)&w1l[(k4 * 4 + kk) * 128 + 64 + jg * 4];
#pragma unroll
      for (int i = 0; i < 4; ++i) {
        const float zv = ((const float*)&za[i])[kk];
        acc[i][0] = fmaf(zv, w0.x, acc[i][0]);
        acc[i][1] = fmaf(zv, w0.y, acc[i][1]);
        acc[i][2] = fmaf(zv, w0.z, acc[i][2]);
        acc[i][3] = fmaf(zv, w0.w, acc[i][3]);
        acc[i][4] = fmaf(zv, w1.x, acc[i][4]);
        acc[i][5] = fmaf(zv, w1.y, acc[i][5]);
        acc[i][6] = fmaf(zv, w1.z, acc[i][6]);
        acc[i][7] = fmaf(zv, w1.w, acc[i][7]);
      }
    }
  }
  const float4 av0 = *(const float4*)&a1[jg * 4], av1 = *(const float4*)&a1[64 + jg * 4];
  const float4 cv0 = *(const float4*)&c1p[jg * 4], cv1 = *(const float4*)&c1p[64 + jg * 4];
  __syncthreads();  // zl/w1l reads done; accs in regs
  const int sxor = ng & 7;
#pragma unroll
  for (int i = 0; i < 4; ++i) {
    float4 v0, v1;
    v0.x = fmaxf(fmaf(acc[i][0], av0.x, cv0.x), 0.f);
    v0.y = fmaxf(fmaf(acc[i][1], av0.y, cv0.y), 0.f);
    v0.z = fmaxf(fmaf(acc[i][2], av0.z, cv0.z), 0.f);
    v0.w = fmaxf(fmaf(acc[i][3], av0.w, cv0.w), 0.f);
    v1.x = fmaxf(fmaf(acc[i][4], av1.x, cv1.x), 0.f);
    v1.y = fmaxf(fmaf(acc[i][5], av1.y, cv1.y), 0.f);
    v1.z = fmaxf(fmaf(acc[i][6], av1.z, cv1.z), 0.f);
    v1.w = fmaxf(fmaf(acc[i][7], av1.w, cv1.w), 0.f);
    const int g0 = jg ^ sxor, g1i = 16 + (jg ^ sxor);
    *(float4*)&z1l[(n0 + i) * 128 + g0 * 4] = v0;
    *(float4*)&z1l[(n0 + i) * 128 + g1i * 4] = v1;
  }
  for (int i = tid; i < 2048; i += 256)
    *(float4*)&w2l[i * 4] = *(const float4*)&W2g[i * 4];
  __syncthreads();

  const int jb = (tid & 7) * 8, n0b = (tid >> 3) * 2;
  const float4 b20 = *(const float4*)&b2[jb], b21 = *(const float4*)&b2[jb + 4];
  float accB[2][8];
#pragma unroll
  for (int i = 0; i < 2; ++i) {
    accB[i][0] = b20.x; accB[i][1] = b20.y; accB[i][2] = b20.z; accB[i][3] = b20.w;
    accB[i][4] = b21.x; accB[i][5] = b21.y; accB[i][6] = b21.z; accB[i][7] = b21.w;
  }
#pragma unroll 2
  for (int k4 = 0; k4 < 32; ++k4) {
    float4 zb[2];
#pragma unroll
    for (int i = 0; i < 2; ++i) {
      const int n = n0b + i;
      const int gs = k4 ^ ((n >> 2) & 7);
      zb[i] = *(const float4*)&z1l[n * 128 + gs * 4];
    }
#pragma unroll
    for (int kk = 0; kk < 4; ++kk) {
      const float4 w0 = *(const float4*)&w2l[(k4 * 4 + kk) * 64 + jb];
      const float4 w1 = *(const float4*)&w2l[(k4 * 4 + kk) * 64 + jb + 4];
#pragma unroll
      for (int i = 0; i < 2; ++i) {
        const float zv = ((const float*)&zb[i])[kk];
        accB[i][0] = fmaf(zv, w0.x, accB[i][0]);
        accB[i][1] = fmaf(zv, w0.y, accB[i][1]);
        accB[i][2] = fmaf(zv, w0.z, accB[i][2]);
        accB[i][3] = fmaf(zv, w0.w, accB[i][3]);
        accB[i][4] = fmaf(zv, w1.x, accB[i][4]);
        accB[i][5] = fmaf(zv, w1.y, accB[i][5]);
        accB[i][6] = fmaf(zv, w1.z, accB[i][6]);
        accB[i][7] = fmaf(zv, w1.w, accB[i][7]);
      }
    }
  }
  float sj[8], qj[8];
#pragma unroll
  for (int c = 0; c < 8; ++c) { sj[c] = 0.f; qj[c] = 0.f; }
#pragma unroll
  for (int i = 0; i < 2; ++i) {
    const int n = n0b + i;
    if (n < nlim) {
      float4 o0, o1;
      o0.x = accB[i][0]; o0.y = accB[i][1]; o0.z = accB[i][2]; o0.w = accB[i][3];
      o1.x = accB[i][4]; o1.y = accB[i][5]; o1.z = accB[i][6]; o1.w = accB[i][7];
      *(float4*)&zout[(size_t)(nb + n) * 64 + jb] = o0;
      *(float4*)&zout[(size_t)(nb + n) * 64 + jb + 4] = o1;
#pragma unroll
      for (int c = 0; c < 8; ++c) {
        sj[c] += accB[i][c];
        qj[c] = fmaf(accB[i][c], accB[i][c], qj[c]);
      }
    }
  }
#pragma unroll
  for (int c = 0; c < 8; ++c) {
    atomicAdd(&ss[jb + c], sj[c]);
    atomicAdd(&sq[jb + c], qj[c]);
  }
  __syncthreads();
  if (tid < 64) {
    atomicAdd(&s2[tid], ss[tid]);
    atomicAdd(&q2[tid], sq[tid]);
  }
}

__global__ void k_finalize(const float* __restrict__ sum, const float* __restrict__ sq,
                           const float* __restrict__ g, const float* __restrict__ b,
                           float* __restrict__ a, float* __restrict__ c) {
  int j = threadIdx.x;
  const float inv = 1.0f / (float)N_NODES;
  float m = sum[j] * inv;
  float v = sq[j] * inv - m * m;
  float r = rsqrtf(v + 1e-5f);
  float aa = g[j] * r;
  a[j] = aa;
  c[j] = fmaf(-m, aa, b[j]);
}

// ---------------- pool: batch sorted -> one wave per graph, zero atomics ----
__global__ void __launch_bounds__(256)
k_pool(const float* __restrict__ z2, const float* __restrict__ a2,
       const float* __restrict__ c2, const int* __restrict__ batch,
       float* __restrict__ out) {
  int g = blockIdx.x * 4 + (threadIdx.x >> 6);
  int d = threadIdx.x & 63;
  int a = 0, b = N_NODES;
  while (a < b) { int m = (a + b) >> 1; if (batch[m] < g) a = m + 1; else b = m; }
  const int lo = a;
  b = N_NODES;
  while (a < b) { int m = (a + b) >> 1; if (batch[m] < g + 1) a = m + 1; else b = m; }
  const int hi = a;
  float s0 = 0.f, s1 = 0.f, s2 = 0.f, s3 = 0.f;
  int n = lo;
  for (; n + 4 <= hi; n += 4) {
    s0 += z2[(size_t)(n + 0) * 64 + d];
    s1 += z2[(size_t)(n + 1) * 64 + d];
    s2 += z2[(size_t)(n + 2) * 64 + d];
    s3 += z2[(size_t)(n + 3) * 64 + d];
  }
  for (; n < hi; ++n) s0 += z2[(size_t)n * 64 + d];
  float S = (s0 + s1) + (s2 + s3);
  float cntf = (float)(hi - lo);
  out[g * 64 + d] = fmaf(S, a2[d], cntf * c2[d]) / (cntf + 1e-9f);
}

extern "C" void kernel_launch(void* const* d_in, const int* in_sizes, int n_in,
                              void* d_out, int out_size, void* d_ws, size_t ws_size,
                              hipStream_t stream) {
  const int* x = (const int*)d_in[0];
  const int* ea = (const int*)d_in[1];
  const int* ei = (const int*)d_in[2];
  const int* batch = (const int*)d_in[3];
  const float* atom_emb = (const float*)d_in[4];
  const float* bond_emb = (const float*)d_in[5];
  const float* W1 = (const float*)d_in[6];
  const float* g1 = (const float*)d_in[8];
  const float* be1 = (const float*)d_in[9];
  const float* W2 = (const float*)d_in[10];
  const float* b2 = (const float*)d_in[11];
  const float* eps = (const float*)d_in[12];
  const float* bn_g = (const float*)d_in[13];
  const float* bn_b = (const float*)d_in[14];

  float* w = (float*)d_ws;
  float* A = w;                                 // h0, then z2
  float* B = w + (size_t)N_NODES * 64;
  float* stats = B + (size_t)N_NODES * 64;      // 4x(cs|M) = 16640
  float* s2 = stats + 16640;
  float* q2 = stats + 16704;
  float* a1 = stats + 16768;
  float* c1p = stats + 16896;
  float* a2 = stats + 17024;
  float* c2 = stats + 17088;
  int* ptr = (int*)(stats + 17152);             // 100001
  int* deg = ptr + (N_NODES + 1);               // 100000
  unsigned int* csr = (unsigned int*)(deg + N_NODES);  // 1.6M
  int* bs = (int*)(csr + N_EDGES);              // 391

  const int NBLK = (N_NODES + 255) / 256;   // 391
  const int NTILE = (N_NODES + 63) / 64;    // 1563
  const int NPULL = N_NODES / 32;           // 3125 (exact)
  const int NZ = (N_NODES + 255) / 256;     // 391 (4 tiles of 64 per block)

  hipMemsetAsync(deg, 0, N_NODES * sizeof(int), stream);

  k_atom_embed<<<N_NODES / 4, 256, 0, stream>>>(x, atom_emb, A);

  // CSR build (once; reused across all 4 layers)
  k_hist<<<(N_EDGES + 255) / 256, 256, 0, stream>>>(ei, deg);
  k_scan1<<<NBLK, 256, 0, stream>>>(deg, bs);
  k_scan2<<<1, 512, 0, stream>>>(bs, NBLK);
  k_scan3<<<NBLK, 256, 0, stream>>>(deg, bs, ptr);
  k_fill<<<(N_EDGES + 255) / 256, 256, 0, stream>>>(ei, ea, deg, csr);

  for (int l = 0; l < NL; ++l) {
    k_pull<<<NPULL, 256, 0, stream>>>(
        A, csr, ptr, bond_emb + (size_t)l * 1536, a2, c2, eps + l,
        (l > 0) ? 1 : 0, B, stats);
    k_zstats<<<NZ, 256, 0, stream>>>(B, stats);
    k_fin1<<<1, 128, 0, stream>>>(stats, W1 + (size_t)l * 8192,
                                  g1 + l * 128, be1 + l * 128, a1, c1p);
    k_mm2<<<NTILE, 256, 0, stream>>>(
        B, W1 + (size_t)l * 8192, a1, c1p, W2 + (size_t)l * 8192, b2 + l * 64,
        A, s2, q2);
    k_finalize<<<1, 64, 0, stream>>>(s2, q2, bn_g + l * 64, bn_b + l * 64, a2, c2);
  }
  k_pool<<<NG / 4, 256, 0, stream>>>(A, a2, c2, batch, (float*)d_out);
}